// Round 9
// baseline (2057.206 us; speedup 1.0000x reference)
//
#include <hip/hip_runtime.h>
#include <hip/hip_bf16.h>
#include <math.h>

// GGNN: L=5 layers of { m = h@W_l ; agg = scatter_add(ew * m[src] -> dst) ;
//                       h = GRUCell(agg, h) } then out = relu(h)@fc_w^T + fc_b
// H=256, N=50000, E=800000.
//
// R15: weight folding deleted m_gemm. R17/R18: dual-layout h (tiled for
// gates staging, blocked hB for spmm gather) + repack kernel.
// R19 (this round): counted-vmcnt pipeline in gates_k (T3+T4 port).
//   BK=32 chunks, ONE B-matrix per chunk (dolo split into two chunks that
//   re-stage A) -> every wave stages exactly 4 glds (wave-uniform counts).
//   3 slabs x 16KB (48KB, 3 blocks/CU), depth-3 rotation. Per chunk:
//   ds_read af+bf -> lgkmcnt(0) -> vmcnt(4) -> s_barrier -> stage(c+3)
//   -> setprio(1) MFMA setprio(0). One barrier/chunk, NO vmcnt(0) drain in
//   steady state (m218: counted-vs-drain = +38-73%). Zero-gate B strips are
//   staged (zeros in memory) to keep counts uniform. MFMA work unchanged.
//   Fallback to R12 2-slab path when !(fullsplit && useHL).

#define HDIM 256

using bf16x8 = __attribute__((ext_vector_type(8))) short;
using f32x4  = __attribute__((ext_vector_type(4))) float;

__device__ __forceinline__ bf16x8 ldfrag(const ushort* p) {
    union { uint4 u; bf16x8 f; } x;
    x.u = *(const uint4*)p;
    return x.f;
}
#define MFMA(a, b, c) __builtin_amdgcn_mfma_f32_16x16x32_bf16((a), (b), (c), 0, 0, 0)
#define GLD16(g, l)                                                            \
    __builtin_amdgcn_global_load_lds(                                          \
        (const __attribute__((address_space(1))) void*)(g),                    \
        (__attribute__((address_space(3))) void*)(l), 16, 0, 0)
#define VMW8() asm volatile("s_waitcnt vmcnt(8)" ::: "memory")
#define VMW4() asm volatile("s_waitcnt vmcnt(4)" ::: "memory")
#define VMW0() asm volatile("s_waitcnt vmcnt(0)" ::: "memory")
#define LGW()  asm volatile("s_waitcnt lgkmcnt(0)" ::: "memory")
#define SBAR() __builtin_amdgcn_s_barrier()

__device__ __forceinline__ float ldf(const void* p, size_t i, int isbf) {
    if (isbf) return __bfloat162float(((const __hip_bfloat16*)p)[i]);
    return ((const float*)p)[i];
}
__device__ __forceinline__ ushort f2bs(float v) {
    __hip_bfloat16 b = __float2bfloat16(v);
    return *(ushort*)&b;
}
__device__ __forceinline__ float bs2f(ushort u) {
    __hip_bfloat16 b = *(__hip_bfloat16*)&u;
    return __bfloat162float(b);
}
// tiled plane addr, K-extent 256 (h planes): 16x32 fragment tiles of 512 halves
__device__ __forceinline__ size_t taddrH(int n, int k) {
    return (size_t)(n >> 4) * 4096 + (size_t)((k >> 5) << 9)
         + (size_t)(((k >> 3) & 3) << 7) + (size_t)((n & 15) << 3) + (k & 7);
}
// tiled plane addr, K-extent 512 (S hi|lo combined) — AGG only
__device__ __forceinline__ size_t taddrA(int n, int k) {
    return (size_t)(n >> 4) * 8192 + (size_t)((k >> 5) << 9)
         + (size_t)(((k >> 3) & 3) << 7) + (size_t)((n & 15) << 3) + (k & 7);
}

// flags[0] = 1 if float tensors are bf16, 0 if f32
// flags[1] = 1 if edge_index is int64, 0 if int32
__global__ void detect_k(const void* x, const void* ei, int* flags) {
    if (blockIdx.x == 0 && threadIdx.x == 0) {
        const __hip_bfloat16* xb = (const __hip_bfloat16*)x;
        int isbf = 1;
        for (int i = 0; i < 1024; ++i) {
            float v = fabsf(__bfloat162float(xb[i]));
            if (!(v < 1e6f)) { isbf = 0; break; }
        }
        flags[0] = isbf;
        const int* e32 = (const int*)ei;
        int orv = e32[1] | e32[3] | e32[5] | e32[7] | e32[9] | e32[11];
        flags[1] = (orv == 0) ? 1 : 0;
    }
}

// x -> tiled h planes + blocked hB plane; pad rows zeroed
__global__ void conv_h0_k(const void* x, ushort* HH, ushort* HL, ushort* hB,
                          const int* flags, int useHL, int Nn, size_t npad256) {
    size_t i = (size_t)blockIdx.x * blockDim.x + threadIdx.x;
    if (i >= npad256) return;
    const int n = (int)(i >> 8), k = (int)(i & 255);
    float v = 0.f;
    if (n < Nn) v = ldf(x, i, flags[0]);
    const ushort hi = f2bs(v);
    const ushort lo = f2bs(v - bs2f(hi));
    const size_t a = taddrH(n, k);
    HH[a] = hi;
    if (useHL) HL[a] = lo;
    hB[(size_t)n * 512 + k] = hi;
    hB[(size_t)n * 512 + 256 + k] = lo;
}

// tiled h planes -> blocked hB. Each thread moves one 8-half fragment (16B)
// of hi + the matching lo.
__global__ void repack_k(const ushort* __restrict__ TH, const ushort* __restrict__ TL,
                         ushort* __restrict__ hB, int useHL, int ngroups) {
    const int g = blockIdx.x * 256 + threadIdx.x;
    if (g >= ngroups) return;
    const int t = g >> 9, o = (g & 511) * 8;
    const int k = ((o >> 9) << 5) | (((o >> 7) & 3) << 3);
    const int n = t * 16 + ((o >> 3) & 15);
    const uint4 hv = *(const uint4*)&TH[(size_t)t * 4096 + o];
    *(uint4*)&hB[(size_t)n * 512 + k] = hv;
    uint4 lv;
    if (useHL) lv = *(const uint4*)&TL[(size_t)t * 4096 + o];
    else       lv = make_uint4(0u, 0u, 0u, 0u);
    *(uint4*)&hB[(size_t)n * 512 + 256 + k] = lv;
}

// WihP[l][r][k] = sum_j Wih[r][j] * W[l][k][j]  (f32, 16x16-tiled, LDS-staged)
__global__ __launch_bounds__(256)
void prep1_k(const void* wih, const void* w, float* wihp, const int* flags) {
    __shared__ float As[16][260], Bs[16][260];
    const int bx = blockIdx.x;            // l*768 + rt16*16 + kt16
    const int l = bx / 768, rem = bx % 768;
    const int rt = (rem >> 4) << 4, kt = (rem & 15) << 4;
    const int tid = threadIdx.x, isbf = flags[0];
    for (int idx = tid; idx < 4096; idx += 256) {
        const int row = idx >> 8, col = idx & 255;
        As[row][col] = ldf(wih, (size_t)(rt + row) * 256 + col, isbf);
        Bs[row][col] = ldf(w, (size_t)l * 65536 + (size_t)(kt + row) * 256 + col, isbf);
    }
    __syncthreads();
    const int ri = tid >> 4, ki = tid & 15;
    float acc = 0.f;
    for (int j = 0; j < 256; ++j) acc = fmaf(As[ri][j], Bs[ki][j], acc);
    wihp[((size_t)l * 768 + rt + ri) * 256 + kt + ki] = acc;
}

// Build tiled gate-B matrices + biases.
// BgA[l] [1024 out][512 k] (k segs = S hi / S lo), out col j: g=(j>>4)&3,
//   b=16*(j>>6)+(j&15): g in {r,z,ni}: WihP[l][g*256+b][kk]; nh: 0.
// BgB (shared) [1024 out][512 k] (k segs = h hi / h lo): g in {r,z}:
//   Whh[g*256+b][kk]; nh: Whh[512+b][kk]; ni: 0.
__global__ void prep2_k(const float* __restrict__ wihp, const void* whh,
                        const void* bih, const void* bhh,
                        ushort* BgAH, ushort* BgAL, ushort* BgBH, ushort* BgBL,
                        float* bsum, float* bni, float* bnh,
                        const int* flags, int L) {
    const int i = blockIdx.x * blockDim.x + threadIdx.x;
    const int isbf = flags[0];
    if (i < (L << 19)) {
        const int l = i >> 19, r2 = i & 524287;
        const int j = r2 >> 9, k = r2 & 511;
        const int g = (j >> 4) & 3, b = ((j >> 6) << 4) + (j & 15);
        const int kk = k & 255;
        const float v = (g == 3) ? 0.f
                      : wihp[((size_t)l * 768 + g * 256 + b) * 256 + kk];
        const ushort hi = f2bs(v);
        const int ct = j >> 4, c = k >> 5;
        const size_t a = (size_t)l * 524288 + (size_t)(ct * 16 + c) * 512
                       + (size_t)(((k >> 3) & 3) << 7) + ((j & 15) << 3) + (k & 7);
        BgAH[a] = hi; BgAL[a] = f2bs(v - bs2f(hi));
    }
    if (i < 524288) {
        const int j = i >> 9, k = i & 511;
        const int g = (j >> 4) & 3, b = ((j >> 6) << 4) + (j & 15);
        const int kk = k & 255;
        float v;
        if (g == 0)      v = ldf(whh, (size_t)b * 256 + kk, isbf);
        else if (g == 1) v = ldf(whh, (size_t)(256 + b) * 256 + kk, isbf);
        else if (g == 2) v = 0.f;
        else             v = ldf(whh, (size_t)(512 + b) * 256 + kk, isbf);
        const ushort hi = f2bs(v);
        const int ct = j >> 4, c = k >> 5;
        const size_t a = (size_t)(ct * 16 + c) * 512
                       + (size_t)(((k >> 3) & 3) << 7) + ((j & 15) << 3) + (k & 7);
        BgBH[a] = hi; BgBL[a] = f2bs(v - bs2f(hi));
    }
    if (i < 512) bsum[i] = ldf(bih, i, isbf) + ldf(bhh, i, isbf);
    if (i < 256) {
        bni[i] = ldf(bih, 512 + i, isbf);
        bnh[i] = ldf(bhh, 512 + i, isbf);
    }
}

// ---------------- CSR build (by dst), once per call ----------------

__global__ void zero_int_k(int* p, int n) {
    int i = blockIdx.x * blockDim.x + threadIdx.x;
    if (i < n) p[i] = 0;
}

__global__ void count_k(const void* ei, int* cnt, const int* flags, int E) {
    int e = blockIdx.x * blockDim.x + threadIdx.x;
    if (e >= E) return;
    const int* e32 = (const int*)ei;
    int d = flags[1] ? e32[2 * ((size_t)E + e)] : e32[(size_t)E + e];
    atomicAdd(&cnt[d], 1);
}

__global__ __launch_bounds__(256)
void scan1_k(const int* cnt, int* ptr, int* bsumN, int N) {
    __shared__ int s[256];
    const int t = threadIdx.x;
    const int gid = blockIdx.x * 256 + t;
    int v = (gid < N) ? cnt[gid] : 0;
    const int own = v;
    s[t] = v;
    __syncthreads();
#pragma unroll
    for (int off = 1; off < 256; off <<= 1) {
        int add = (t >= off) ? s[t - off] : 0;
        __syncthreads();
        s[t] += add;
        __syncthreads();
    }
    if (gid < N) ptr[gid] = s[t] - own;
    if (t == 255) bsumN[blockIdx.x] = s[255];
}

__global__ __launch_bounds__(256)
void scan2_k(int* bsumN, int NB) {
    __shared__ int s[256];
    __shared__ int carry;
    const int t = threadIdx.x;
    if (t == 0) carry = 0;
    __syncthreads();
    for (int base = 0; base < NB; base += 256) {
        const int i = base + t;
        int v = (i < NB) ? bsumN[i] : 0;
        const int own = v;
        s[t] = v;
        __syncthreads();
#pragma unroll
        for (int off = 1; off < 256; off <<= 1) {
            int add = (t >= off) ? s[t - off] : 0;
            __syncthreads();
            s[t] += add;
            __syncthreads();
        }
        if (i < NB) bsumN[i] = carry + s[t] - own;
        __syncthreads();
        if (t == 0) carry += s[255];
        __syncthreads();
    }
}

__global__ void scan3_k(int* ptr, int* cursor, const int* bsumN, int N, int E) {
    const int gid = blockIdx.x * 256 + threadIdx.x;
    if (gid < N) {
        const int p = ptr[gid] + bsumN[blockIdx.x];
        ptr[gid] = p;
        cursor[gid] = p;
    }
    if (gid == 0) ptr[N] = E;
}

__global__ void fill_k(const void* ei, const void* ew, int* cursor,
                       int* srcs, float* wse, const int* flags, int E) {
    int e = blockIdx.x * blockDim.x + threadIdx.x;
    if (e >= E) return;
    const int* e32 = (const int*)ei;
    int s, d;
    if (flags[1]) { s = e32[2 * (size_t)e]; d = e32[2 * ((size_t)E + e)]; }
    else          { s = e32[e];             d = e32[(size_t)E + e]; }
    const int p = atomicAdd(&cursor[d], 1);
    srcs[p] = s;
    wse[p] = ldf(ew, e, flags[0]);
}

// ---------------- SpMM gather: S[d] = sum_j w_j * h[src_j] ------------------
// hB blocked [n][512] (hi row | lo row): ONE 16B load per lane per edge.
// Lane l<32 accumulates hi dims 8l..8l+7; lane l+32 the matching lo dims.
// shfl_xor(32) combines; lanes 0..31 write S hi/lo 16B frags to tiled AGG.
__global__ __launch_bounds__(256)
void spmm_k(const ushort* __restrict__ hB, const int* __restrict__ ptr,
            const int* __restrict__ srcs, const float* __restrict__ wse,
            ushort* __restrict__ AGG, int N) {
    const int node = blockIdx.x * 4 + (threadIdx.x >> 6);
    if (node >= N) return;
    const int lane = threadIdx.x & 63;
    const int p0 = ptr[node], p1 = ptr[node + 1];
    float av[8];
#pragma unroll
    for (int i = 0; i < 8; ++i) av[i] = 0.f;
    union U8 { ushort u[8]; uint4 v; };
    int j = p0;
    for (; j + 1 < p1; j += 2) {
        const int s0 = srcs[j], s1 = srcs[j + 1];
        const float w0 = wse[j], w1 = wse[j + 1];
        U8 u0, u1;
        u0.v = *(const uint4*)&hB[(size_t)s0 * 512 + lane * 8];
        u1.v = *(const uint4*)&hB[(size_t)s1 * 512 + lane * 8];
#pragma unroll
        for (int i = 0; i < 8; ++i) av[i] = fmaf(w0, bs2f(u0.u[i]), av[i]);
#pragma unroll
        for (int i = 0; i < 8; ++i) av[i] = fmaf(w1, bs2f(u1.u[i]), av[i]);
    }
    if (j < p1) {
        const int s0 = srcs[j];
        const float w0 = wse[j];
        U8 u0;
        u0.v = *(const uint4*)&hB[(size_t)s0 * 512 + lane * 8];
#pragma unroll
        for (int i = 0; i < 8; ++i) av[i] = fmaf(w0, bs2f(u0.u[i]), av[i]);
    }
#pragma unroll
    for (int i = 0; i < 8; ++i) av[i] += __shfl_xor(av[i], 32);
    if (lane < 32) {
        const int k0 = lane * 8;
        union U8 hi8, lo8;
#pragma unroll
        for (int i = 0; i < 8; ++i) {
            const ushort hi = f2bs(av[i]);
            hi8.u[i] = hi;
            lo8.u[i] = f2bs(av[i] - bs2f(hi));
        }
        *(uint4*)&AGG[taddrA(node, k0)] = hi8.v;
        *(uint4*)&AGG[taddrA(node, 256 + k0)] = lo8.v;
    }
}

// ---------------- gates GEMM + fused GRU ------------------------------------
// Fast path (fullsplit && useHL): 48 BK=32 chunks, one B per chunk:
//   c0-7:   S-hi x BgAH(0-7),  jskip 3
//   c8-15:  S-hi x BgAL(0-7),  jskip 3   (lo-B on A-hi)
//   c16-23: S-lo x BgAH(8-15), jskip 3
//   c24-31: hH   x BgBH(0-7),  jskip 2
//   c32-39: hH   x BgBL(0-7),  jskip 2
//   c40-47: hL   x BgBH(8-15), jskip 2
// 3 slabs x 8192 halves (A|B), depth-3 counted-vmcnt pipeline (see header).
// Fallback: R12 2-slab full-drain path (any flag combo).
__global__ __launch_bounds__(256)
void gates_k(const ushort* __restrict__ AGG,
             const ushort* __restrict__ HH, const ushort* __restrict__ HL,
             const ushort* __restrict__ BgAH, const ushort* __restrict__ BgAL,
             const ushort* __restrict__ BgBH, const ushort* __restrict__ BgBL,
             const float* __restrict__ bsum, const float* __restrict__ bni,
             const float* __restrict__ bnh,
             ushort* __restrict__ HnH, ushort* __restrict__ HnL,
             const int* __restrict__ flags, int useHL, int nRB) {
    __shared__ ushort lds[24576];  // fast: 3 x (A 4096|B 4096); fb: 2 x 12288
    const int x = blockIdx.x & 7, rem = blockIdx.x >> 3;
    const int cgB = rem & 7, rbHi = rem >> 3;
    const int rb = rbHi * 8 + x;
    if (rb >= nRB) return;
    const int tid = threadIdx.x, lane = tid & 63;
    const int wv = __builtin_amdgcn_readfirstlane(tid >> 6);
    const int wr = wv & 1, wc = wv >> 1;
    const int lm = lane & 15, lq = lane >> 4;
    const int fullsplit = !flags[0];
    const int rt = rb * 8, t0 = 2 * wv;
    f32x4 acc[4][4];
#pragma unroll
    for (int i = 0; i < 4; ++i)
#pragma unroll
        for (int j = 0; j < 4; ++j) acc[i][j] = (f32x4){0.f, 0.f, 0.f, 0.f};

    if (fullsplit && useHL) {
        // ---- counted-vmcnt pipeline ----
        auto stage = [&](int xx, int sl3) {
            const ushort* a0;
            size_t astride;
            if (xx < 24) {
                const int ck = (xx < 16) ? (xx & 7) : (xx - 8);
                a0 = AGG + (size_t)(rt + t0) * 8192 + (size_t)ck * 512;
                astride = 8192;
            } else {
                const ushort* hp = (xx < 40) ? HH : HL;
                const int ck = (xx < 40) ? ((xx - 24) & 7) : (xx - 40);
                a0 = hp + (size_t)(rt + t0) * 4096 + (size_t)ck * 512;
                astride = 4096;
            }
            const ushort* B;
            int cl;
            if (xx < 8)       { B = BgAH; cl = xx; }
            else if (xx < 16) { B = BgAL; cl = xx - 8; }
            else if (xx < 24) { B = BgAH; cl = xx - 8; }   // 8..15
            else if (xx < 32) { B = BgBH; cl = xx - 24; }
            else if (xx < 40) { B = BgBL; cl = xx - 32; }
            else              { B = BgBH; cl = xx - 32; }  // 8..15
            const size_t bb = ((size_t)(8 * cgB + t0) * 16 + (size_t)cl) * 512;
            ushort* sl = &lds[sl3 * 8192];
            GLD16(a0 + (size_t)lane * 8, sl + t0 * 512);
            GLD16(a0 + astride + (size_t)lane * 8, sl + t0 * 512 + 512);
            GLD16(B + bb + (size_t)lane * 8, sl + 4096 + t0 * 512);
            GLD16(B + bb + 8192 + (size_t)lane * 8, sl + 4096 + t0 * 512 + 512);
        };
        stage(0, 0); stage(1, 1); stage(2, 2);
        VMW8();   // 12 in flight -> wait stage(0) (outstanding <= n1+n2 = 8)
        SBAR();
#pragma unroll
        for (int c = 0; c < 48; ++c) {
            const ushort* sl = &lds[(c % 3) * 8192];
            const size_t boff = (size_t)lq * 128 + (size_t)lm * 8;
            bf16x8 af[4];
#pragma unroll
            for (int i = 0; i < 4; ++i)
                af[i] = ldfrag(sl + (4 * wr + i) * 512 + boff);
            const bf16x8 bf0 = ldfrag(sl + 4096 + (4 * wc + 0) * 512 + boff);
            const bf16x8 bf1 = ldfrag(sl + 4096 + (4 * wc + 1) * 512 + boff);
            const bf16x8 bf2 = ldfrag(sl + 4096 + (4 * wc + ((c < 24) ? 2 : 3)) * 512 + boff);
            LGW();                       // my reads of slab c%3 complete
            if (c < 46) { VMW4(); }      // my stage(c+1) complete (c+2 may fly)
            else        { VMW0(); }      // tail drain
            SBAR();                      // all reads done + stage(c+1) visible
            if (c + 3 < 48) stage(c + 3, (c + 3) % 3);  // overwrite freed slab
            __builtin_amdgcn_s_setprio(1);
#pragma unroll
            for (int i = 0; i < 4; ++i) acc[i][0] = MFMA(af[i], bf0, acc[i][0]);
#pragma unroll
            for (int i = 0; i < 4; ++i) acc[i][1] = MFMA(af[i], bf1, acc[i][1]);
            if (c < 24) {
#pragma unroll
                for (int i = 0; i < 4; ++i) acc[i][2] = MFMA(af[i], bf2, acc[i][2]);
            } else {
#pragma unroll
                for (int i = 0; i < 4; ++i) acc[i][3] = MFMA(af[i], bf2, acc[i][3]);
            }
            __builtin_amdgcn_s_setprio(0);
        }
    } else {
        // ---- fallback: R12 2-slab full-drain path ----
#define GT_STEP(BH, BL, c0l, A0, ASTRIDE, JSKIP, DOLO)                         \
    do {                                                                       \
        __syncthreads();                                                       \
        GLD16((A0) + (size_t)lane * 8, &lds[t0 * 512]);                        \
        GLD16((A0) + (ASTRIDE) + (size_t)lane * 8, &lds[t0 * 512 + 512]);      \
        GLD16((A0) + 512 + (size_t)lane * 8, &lds[12288 + t0 * 512]);          \
        GLD16((A0) + (ASTRIDE) + 512 + (size_t)lane * 8, &lds[12288 + t0 * 512 + 512]); \
        const size_t bb = ((size_t)(8 * cgB + t0) * 16 + (size_t)(c0l)) * 512; \
        if ((t0 & 3) != (JSKIP)) {                                             \
            GLD16((BH) + bb + (size_t)lane * 8, &lds[4096 + t0 * 512]);        \
            GLD16((BH) + bb + 512 + (size_t)lane * 8, &lds[12288 + 4096 + t0 * 512]); \
        }                                                                      \
        if (((t0 + 1) & 3) != (JSKIP)) {                                       \
            GLD16((BH) + bb + 8192 + (size_t)lane * 8, &lds[4096 + t0 * 512 + 512]); \
            GLD16((BH) + bb + 8704 + (size_t)lane * 8, &lds[12288 + 4096 + t0 * 512 + 512]); \
        }                                                                      \
        if (DOLO) {                                                            \
            if ((t0 & 3) != (JSKIP)) {                                         \
                GLD16((BL) + bb + (size_t)lane * 8, &lds[8192 + t0 * 512]);    \
                GLD16((BL) + bb + 512 + (size_t)lane * 8, &lds[12288 + 8192 + t0 * 512]); \
            }                                                                  \
            if (((t0 + 1) & 3) != (JSKIP)) {                                   \
                GLD16((BL) + bb + 8192 + (size_t)lane * 8, &lds[8192 + t0 * 512 + 512]); \
                GLD16((BL) + bb + 8704 + (size_t)lane * 8, &lds[12288 + 8192 + t0 * 512 + 512]); \
            }                                                                  \
        }                                                                      \
        __syncthreads();                                                       \
        _Pragma("unroll")                                                      \
        for (int sb = 0; sb < 2; ++sb) {                                       \
            const int lb = sb * 12288;                                         \
            bf16x8 af[4];                                                      \
            _Pragma("unroll")                                                  \
            for (int i = 0; i < 4; ++i)                                        \
                af[i] = ldfrag(&lds[lb + (4 * wr + i) * 512 + lq * 128 + lm * 8]); \
            _Pragma("unroll")                                                  \
            for (int j = 0; j < 4; ++j) {                                      \
                if (j == (JSKIP)) continue;                                    \
                const bf16x8 bj = ldfrag(&lds[lb + 4096 + (4 * wc + j) * 512 + lq * 128 + lm * 8]); \
                _Pragma("unroll")                                              \
                for (int i = 0; i < 4; ++i) acc[i][j] = MFMA(af[i], bj, acc[i][j]); \
            }                                                                  \
            if (DOLO) {                                                        \
                _Pragma("unroll")                                              \
                for (int j = 0; j < 4; ++j) {                                  \
                    if (j == (JSKIP)) continue;                                \
                    const bf16x8 bl = ldfrag(&lds[lb + 8192 + (4 * wc + j) * 512 + lq * 128 + lm * 8]); \
                    _Pragma("unroll")                                          \
                    for (int i = 0; i < 4; ++i) acc[i][j] = MFMA(af[i], bl, acc[i][j]); \
                }                                                              \
            }                                                                  \
        }                                                                      \
    } while (0)
        for (int s = 0; s < 4; ++s) {
            const ushort* a0 = AGG + (size_t)(rt + t0) * 8192 + (size_t)(2 * s) * 512;
            GT_STEP(BgAH, BgAL, 2 * s, a0, 8192, 3, fullsplit);
        }
        for (int s = 4; s < 8; ++s) {
            const ushort* a0 = AGG + (size_t)(rt + t0) * 8192 + (size_t)(2 * s) * 512;
            GT_STEP(BgAH, BgAL, 2 * s, a0, 8192, 3, 0);
        }
        for (int s = 8; s < 12; ++s) {
            const ushort* a0 = HH + (size_t)(rt + t0) * 4096 + (size_t)(2 * s - 16) * 512;
            GT_STEP(BgBH, BgBL, 2 * s - 16, a0, 4096, 2, fullsplit);
        }
        if (useHL) {
            for (int s = 12; s < 16; ++s) {
                const ushort* a0 = HL + (size_t)(rt + t0) * 4096 + (size_t)(2 * s - 24) * 512;
                GT_STEP(BgBH, BgBL, 2 * s - 16, a0, 4096, 2, 0);
            }
        }
#undef GT_STEP
        __syncthreads();
    }

    // GRU epilogue: col-tile 0..3 = r,z,ni,nh for hidden unit b
    const int b = (2 * cgB + wc) * 16 + lm;
    const float rbias = bsum[b], zbias = bsum[256 + b];
    const float ibias = bni[b], hbias = bnh[b];
#pragma unroll
    for (int i = 0; i < 4; ++i) {
        const int row0 = rb * 128 + wr * 64 + i * 16 + lq * 4;
#pragma unroll
        for (int v = 0; v < 4; ++v) {
            const int row = row0 + v;
            const size_t ho = taddrH(row, b);  // buffers padded; pads benign
            float hold = bs2f(HH[ho]);
            if (useHL) hold += bs2f(HL[ho]);
            const float r = 1.f / (1.f + expf(-(acc[i][0][v] + rbias)));
            const float z = 1.f / (1.f + expf(-(acc[i][1][v] + zbias)));
            const float nn = tanhf(acc[i][2][v] + ibias + r * (acc[i][3][v] + hbias));
            const float hv = (1.f - z) * nn + z * hold;
            const ushort hi = f2bs(hv);
            HnH[ho] = hi;
            if (useHL) HnL[ho] = f2bs(hv - bs2f(hi));
        }
    }
}

// out[n] = sum_t relu(h[n,t]) * fc_w[t] + fc_b ; one 256-thread block per node
__global__ void final_k(const ushort* __restrict__ HH, const ushort* __restrict__ HL,
                        const void* fcw, const void* fcb,
                        void* out, const int* flags, int useHL, int N) {
    const int n = blockIdx.x;
    const int t = threadIdx.x;
    const int isbf = flags[0];
    const size_t off = taddrH(n, t);
    float h = bs2f(HH[off]);
    if (useHL) h += bs2f(HL[off]);
    float v = fmaxf(h, 0.f) * ldf(fcw, t, isbf);
#pragma unroll
    for (int offx = 32; offx >= 1; offx >>= 1) v += __shfl_down(v, offx);
    __shared__ float red[4];
    if ((t & 63) == 0) red[t >> 6] = v;
    __syncthreads();
    if (t == 0) {
        const float s = red[0] + red[1] + red[2] + red[3] + ldf(fcb, 0, isbf);
        if (isbf) ((__hip_bfloat16*)out)[n] = __float2bfloat16(s);
        else      ((float*)out)[n] = s;
    }
}

extern "C" void kernel_launch(void* const* d_in, const int* in_sizes, int n_in,
                              void* d_out, int out_size, void* d_ws, size_t ws_size,
                              hipStream_t stream) {
    const int H = HDIM;
    const int N = in_sizes[0] / H;       // 50000
    const int E = in_sizes[2];           // 800000
    const int L = in_sizes[3] / (H * H); // 5
    const int NB = (N + 255) / 256;
    const int nRB = (N + 127) / 128;     // 391
    const size_t NPAD = (size_t)nRB * 128;
    const size_t hHalf = NPAD * 256;     // halves per tiled h plane
    const size_t aggHalf = NPAD * 512;

    char* p = (char*)d_ws;
    int*    flags = (int*)p;              p += 64;
    ushort* AGG  = (ushort*)p;            p += aggHalf * 2;
    ushort* HxH  = (ushort*)p;            p += hHalf * 2;
    ushort* HyH  = (ushort*)p;            p += hHalf * 2;
    ushort* hB   = (ushort*)p;            p += NPAD * 512 * 2;   // blocked plane
    float*  wihp = (float*)p;             p += (size_t)L * 768 * 256 * 4;
    ushort* BgAH = (ushort*)p;            p += (size_t)L * 524288 * 2;
    ushort* BgAL = (ushort*)p;            p += (size_t)L * 524288 * 2;
    ushort* BgBH = (ushort*)p;            p += (size_t)524288 * 2;
    ushort* BgBL = (ushort*)p;            p += (size_t)524288 * 2;
    float*  bsum = (float*)p;             p += 512 * 4;
    float*  bni  = (float*)p;             p += 256 * 4;
    float*  bnh  = (float*)p;             p += 256 * 4;
    int*    ptr  = (int*)p;               p += (size_t)(N + 1) * 4;
    int*    cursor = (int*)p;             p += (size_t)N * 4;
    int*    bsumN  = (int*)p;             p += (size_t)NB * 4;
    int*    srcs   = (int*)p;             p += (size_t)E * 4;
    float*  wse    = (float*)p;           p += (size_t)E * 4;
    const size_t need_reduced = (size_t)(p - (char*)d_ws);
    ushort* HxL = (ushort*)p;             // optional hi/lo tiled h planes
    ushort* HyL = (ushort*)(p + hHalf * 2);
    const size_t need_full = need_reduced + 2 * hHalf * 2;
    const int useHL = (ws_size >= need_full) ? 1 : 0;
    if (!useHL) { HxL = HxH; HyL = HyH; }  // never dereferenced when useHL=0

    detect_k<<<dim3(1), dim3(64), 0, stream>>>(d_in[0], d_in[1], flags);
    conv_h0_k<<<dim3((unsigned)NPAD), dim3(256), 0, stream>>>(
        d_in[0], HxH, HxL, hB, flags, useHL, N, NPAD * 256);
    prep1_k<<<dim3((unsigned)(L * 768)), dim3(256), 0, stream>>>(
        d_in[4], d_in[3], wihp, flags);
    prep2_k<<<dim3((unsigned)(L * 2048)), dim3(256), 0, stream>>>(
        wihp, d_in[5], d_in[6], d_in[7],
        BgAH, BgAL, BgBH, BgBL, bsum, bni, bnh, flags, L);

    zero_int_k<<<dim3(NB), dim3(256), 0, stream>>>(cursor, N);
    count_k<<<dim3((E + 255) / 256), dim3(256), 0, stream>>>(d_in[1], cursor, flags, E);
    scan1_k<<<dim3(NB), dim3(256), 0, stream>>>(cursor, ptr, bsumN, N);
    scan2_k<<<dim3(1), dim3(256), 0, stream>>>(bsumN, NB);
    scan3_k<<<dim3(NB), dim3(256), 0, stream>>>(ptr, cursor, bsumN, N, E);
    fill_k<<<dim3((E + 255) / 256), dim3(256), 0, stream>>>(
        d_in[1], d_in[2], cursor, srcs, wse, flags, E);

    const dim3 blk(256);
    const unsigned gGrid = 64u * (unsigned)((nRB + 7) / 8);
    const int ngroups = (int)(NPAD * 32);      // fragments per plane
    const unsigned rGrid = (unsigned)((ngroups + 255) / 256);
    ushort *HcH = HxH, *HcL = HxL, *HnH = HyH, *HnL = HyL;
    for (int l = 0; l < L; ++l) {
        spmm_k<<<dim3((N + 3) / 4), blk, 0, stream>>>(hB, ptr, srcs, wse, AGG, N);
        gates_k<<<dim3(gGrid), blk, 0, stream>>>(
            AGG, HcH, HcL,
            BgAH + (size_t)l * 524288, BgAL + (size_t)l * 524288,
            BgBH, BgBL, bsum, bni, bnh, HnH, HnL, flags, useHL, nRB);
        if (l + 1 < L)
            repack_k<<<dim3(rGrid), blk, 0, stream>>>(HnH, HnL, hB, useHL, ngroups);
        ushort* t;
        t = HcH; HcH = HnH; HnH = t;
        t = HcL; HcL = HnL; HnL = t;
    }
    final_k<<<dim3(N), blk, 0, stream>>>(
        HcH, HcL, d_in[8], d_in[9], d_out, flags, useHL, N);
}

// Round 10
// 1925.217 us; speedup vs baseline: 1.0686x; 1.0686x over previous
//
#include <hip/hip_runtime.h>
#include <hip/hip_bf16.h>
#include <math.h>

// GGNN: L=5 layers of { m = h@W_l ; agg = scatter_add(ew * m[src] -> dst) ;
//                       h = GRUCell(agg, h) } then out = relu(h)@fc_w^T + fc_b
// H=256, N=50000, E=800000.
//
// R15: weight folding deleted m_gemm. R17/R18: dual-layout h (tiled for
// gates staging, blocked hB for spmm gather) + repack kernel.
// R19: counted-vmcnt pipeline REGRESSED (162->191): at 128^2/4-wave the
//   overlap doesn't pay (m232 quadrant) and one-B-per-chunk tripled
//   A-staging bytes on a staging-BW-bound kernel. Reverted.
// R20 (this round): gates_k = R12 2-slab full-drain (proven 161.5us, x3
//   confirmations). spmm_k: unroll-4 with all four gather loads issued
//   before FMAs (2 -> 4 independent 16B loads in flight on the
//   srcs->hB dependent chain). No other changes.

#define HDIM 256

using bf16x8 = __attribute__((ext_vector_type(8))) short;
using f32x4  = __attribute__((ext_vector_type(4))) float;

__device__ __forceinline__ bf16x8 ldfrag(const ushort* p) {
    union { uint4 u; bf16x8 f; } x;
    x.u = *(const uint4*)p;
    return x.f;
}
#define MFMA(a, b, c) __builtin_amdgcn_mfma_f32_16x16x32_bf16((a), (b), (c), 0, 0, 0)
#define GLD16(g, l)                                                            \
    __builtin_amdgcn_global_load_lds(                                          \
        (const __attribute__((address_space(1))) void*)(g),                    \
        (__attribute__((address_space(3))) void*)(l), 16, 0, 0)

__device__ __forceinline__ float ldf(const void* p, size_t i, int isbf) {
    if (isbf) return __bfloat162float(((const __hip_bfloat16*)p)[i]);
    return ((const float*)p)[i];
}
__device__ __forceinline__ ushort f2bs(float v) {
    __hip_bfloat16 b = __float2bfloat16(v);
    return *(ushort*)&b;
}
__device__ __forceinline__ float bs2f(ushort u) {
    __hip_bfloat16 b = *(__hip_bfloat16*)&u;
    return __bfloat162float(b);
}
// tiled plane addr, K-extent 256 (h planes): 16x32 fragment tiles of 512 halves
__device__ __forceinline__ size_t taddrH(int n, int k) {
    return (size_t)(n >> 4) * 4096 + (size_t)((k >> 5) << 9)
         + (size_t)(((k >> 3) & 3) << 7) + (size_t)((n & 15) << 3) + (k & 7);
}
// tiled plane addr, K-extent 512 (S hi|lo combined) — AGG only
__device__ __forceinline__ size_t taddrA(int n, int k) {
    return (size_t)(n >> 4) * 8192 + (size_t)((k >> 5) << 9)
         + (size_t)(((k >> 3) & 3) << 7) + (size_t)((n & 15) << 3) + (k & 7);
}

// flags[0] = 1 if float tensors are bf16, 0 if f32
// flags[1] = 1 if edge_index is int64, 0 if int32
__global__ void detect_k(const void* x, const void* ei, int* flags) {
    if (blockIdx.x == 0 && threadIdx.x == 0) {
        const __hip_bfloat16* xb = (const __hip_bfloat16*)x;
        int isbf = 1;
        for (int i = 0; i < 1024; ++i) {
            float v = fabsf(__bfloat162float(xb[i]));
            if (!(v < 1e6f)) { isbf = 0; break; }
        }
        flags[0] = isbf;
        const int* e32 = (const int*)ei;
        int orv = e32[1] | e32[3] | e32[5] | e32[7] | e32[9] | e32[11];
        flags[1] = (orv == 0) ? 1 : 0;
    }
}

// x -> tiled h planes + blocked hB plane; pad rows zeroed
__global__ void conv_h0_k(const void* x, ushort* HH, ushort* HL, ushort* hB,
                          const int* flags, int useHL, int Nn, size_t npad256) {
    size_t i = (size_t)blockIdx.x * blockDim.x + threadIdx.x;
    if (i >= npad256) return;
    const int n = (int)(i >> 8), k = (int)(i & 255);
    float v = 0.f;
    if (n < Nn) v = ldf(x, i, flags[0]);
    const ushort hi = f2bs(v);
    const ushort lo = f2bs(v - bs2f(hi));
    const size_t a = taddrH(n, k);
    HH[a] = hi;
    if (useHL) HL[a] = lo;
    hB[(size_t)n * 512 + k] = hi;
    hB[(size_t)n * 512 + 256 + k] = lo;
}

// tiled h planes -> blocked hB. Each thread moves one 8-half fragment (16B)
// of hi + the matching lo.
__global__ void repack_k(const ushort* __restrict__ TH, const ushort* __restrict__ TL,
                         ushort* __restrict__ hB, int useHL, int ngroups) {
    const int g = blockIdx.x * 256 + threadIdx.x;
    if (g >= ngroups) return;
    const int t = g >> 9, o = (g & 511) * 8;
    const int k = ((o >> 9) << 5) | (((o >> 7) & 3) << 3);
    const int n = t * 16 + ((o >> 3) & 15);
    const uint4 hv = *(const uint4*)&TH[(size_t)t * 4096 + o];
    *(uint4*)&hB[(size_t)n * 512 + k] = hv;
    uint4 lv;
    if (useHL) lv = *(const uint4*)&TL[(size_t)t * 4096 + o];
    else       lv = make_uint4(0u, 0u, 0u, 0u);
    *(uint4*)&hB[(size_t)n * 512 + 256 + k] = lv;
}

// WihP[l][r][k] = sum_j Wih[r][j] * W[l][k][j]  (f32, 16x16-tiled, LDS-staged)
__global__ __launch_bounds__(256)
void prep1_k(const void* wih, const void* w, float* wihp, const int* flags) {
    __shared__ float As[16][260], Bs[16][260];
    const int bx = blockIdx.x;            // l*768 + rt16*16 + kt16
    const int l = bx / 768, rem = bx % 768;
    const int rt = (rem >> 4) << 4, kt = (rem & 15) << 4;
    const int tid = threadIdx.x, isbf = flags[0];
    for (int idx = tid; idx < 4096; idx += 256) {
        const int row = idx >> 8, col = idx & 255;
        As[row][col] = ldf(wih, (size_t)(rt + row) * 256 + col, isbf);
        Bs[row][col] = ldf(w, (size_t)l * 65536 + (size_t)(kt + row) * 256 + col, isbf);
    }
    __syncthreads();
    const int ri = tid >> 4, ki = tid & 15;
    float acc = 0.f;
    for (int j = 0; j < 256; ++j) acc = fmaf(As[ri][j], Bs[ki][j], acc);
    wihp[((size_t)l * 768 + rt + ri) * 256 + kt + ki] = acc;
}

// Build tiled gate-B matrices + biases.
// BgA[l] [1024 out][512 k] (k segs = S hi / S lo), out col j: g=(j>>4)&3,
//   b=16*(j>>6)+(j&15): g in {r,z,ni}: WihP[l][g*256+b][kk]; nh: 0.
// BgB (shared) [1024 out][512 k] (k segs = h hi / h lo): g in {r,z}:
//   Whh[g*256+b][kk]; nh: Whh[512+b][kk]; ni: 0.
__global__ void prep2_k(const float* __restrict__ wihp, const void* whh,
                        const void* bih, const void* bhh,
                        ushort* BgAH, ushort* BgAL, ushort* BgBH, ushort* BgBL,
                        float* bsum, float* bni, float* bnh,
                        const int* flags, int L) {
    const int i = blockIdx.x * blockDim.x + threadIdx.x;
    const int isbf = flags[0];
    if (i < (L << 19)) {
        const int l = i >> 19, r2 = i & 524287;
        const int j = r2 >> 9, k = r2 & 511;
        const int g = (j >> 4) & 3, b = ((j >> 6) << 4) + (j & 15);
        const int kk = k & 255;
        const float v = (g == 3) ? 0.f
                      : wihp[((size_t)l * 768 + g * 256 + b) * 256 + kk];
        const ushort hi = f2bs(v);
        const int ct = j >> 4, c = k >> 5;
        const size_t a = (size_t)l * 524288 + (size_t)(ct * 16 + c) * 512
                       + (size_t)(((k >> 3) & 3) << 7) + ((j & 15) << 3) + (k & 7);
        BgAH[a] = hi; BgAL[a] = f2bs(v - bs2f(hi));
    }
    if (i < 524288) {
        const int j = i >> 9, k = i & 511;
        const int g = (j >> 4) & 3, b = ((j >> 6) << 4) + (j & 15);
        const int kk = k & 255;
        float v;
        if (g == 0)      v = ldf(whh, (size_t)b * 256 + kk, isbf);
        else if (g == 1) v = ldf(whh, (size_t)(256 + b) * 256 + kk, isbf);
        else if (g == 2) v = 0.f;
        else             v = ldf(whh, (size_t)(512 + b) * 256 + kk, isbf);
        const ushort hi = f2bs(v);
        const int ct = j >> 4, c = k >> 5;
        const size_t a = (size_t)(ct * 16 + c) * 512
                       + (size_t)(((k >> 3) & 3) << 7) + ((j & 15) << 3) + (k & 7);
        BgBH[a] = hi; BgBL[a] = f2bs(v - bs2f(hi));
    }
    if (i < 512) bsum[i] = ldf(bih, i, isbf) + ldf(bhh, i, isbf);
    if (i < 256) {
        bni[i] = ldf(bih, 512 + i, isbf);
        bnh[i] = ldf(bhh, 512 + i, isbf);
    }
}

// ---------------- CSR build (by dst), once per call ----------------

__global__ void zero_int_k(int* p, int n) {
    int i = blockIdx.x * blockDim.x + threadIdx.x;
    if (i < n) p[i] = 0;
}

__global__ void count_k(const void* ei, int* cnt, const int* flags, int E) {
    int e = blockIdx.x * blockDim.x + threadIdx.x;
    if (e >= E) return;
    const int* e32 = (const int*)ei;
    int d = flags[1] ? e32[2 * ((size_t)E + e)] : e32[(size_t)E + e];
    atomicAdd(&cnt[d], 1);
}

__global__ __launch_bounds__(256)
void scan1_k(const int* cnt, int* ptr, int* bsumN, int N) {
    __shared__ int s[256];
    const int t = threadIdx.x;
    const int gid = blockIdx.x * 256 + t;
    int v = (gid < N) ? cnt[gid] : 0;
    const int own = v;
    s[t] = v;
    __syncthreads();
#pragma unroll
    for (int off = 1; off < 256; off <<= 1) {
        int add = (t >= off) ? s[t - off] : 0;
        __syncthreads();
        s[t] += add;
        __syncthreads();
    }
    if (gid < N) ptr[gid] = s[t] - own;
    if (t == 255) bsumN[blockIdx.x] = s[255];
}

__global__ __launch_bounds__(256)
void scan2_k(int* bsumN, int NB) {
    __shared__ int s[256];
    __shared__ int carry;
    const int t = threadIdx.x;
    if (t == 0) carry = 0;
    __syncthreads();
    for (int base = 0; base < NB; base += 256) {
        const int i = base + t;
        int v = (i < NB) ? bsumN[i] : 0;
        const int own = v;
        s[t] = v;
        __syncthreads();
#pragma unroll
        for (int off = 1; off < 256; off <<= 1) {
            int add = (t >= off) ? s[t - off] : 0;
            __syncthreads();
            s[t] += add;
            __syncthreads();
        }
        if (i < NB) bsumN[i] = carry + s[t] - own;
        __syncthreads();
        if (t == 0) carry += s[255];
        __syncthreads();
    }
}

__global__ void scan3_k(int* ptr, int* cursor, const int* bsumN, int N, int E) {
    const int gid = blockIdx.x * 256 + threadIdx.x;
    if (gid < N) {
        const int p = ptr[gid] + bsumN[blockIdx.x];
        ptr[gid] = p;
        cursor[gid] = p;
    }
    if (gid == 0) ptr[N] = E;
}

__global__ void fill_k(const void* ei, const void* ew, int* cursor,
                       int* srcs, float* wse, const int* flags, int E) {
    int e = blockIdx.x * blockDim.x + threadIdx.x;
    if (e >= E) return;
    const int* e32 = (const int*)ei;
    int s, d;
    if (flags[1]) { s = e32[2 * (size_t)e]; d = e32[2 * ((size_t)E + e)]; }
    else          { s = e32[e];             d = e32[(size_t)E + e]; }
    const int p = atomicAdd(&cursor[d], 1);
    srcs[p] = s;
    wse[p] = ldf(ew, e, flags[0]);
}

// ---------------- SpMM gather: S[d] = sum_j w_j * h[src_j] ------------------
// hB blocked [n][512] (hi row | lo row): ONE 16B load per lane per edge.
// R20: unroll-4 — four independent gather loads in flight before any FMA
// (srcs->hB dependent chain was only 2-deep). Lane l<32 accumulates hi dims
// 8l..8l+7; lane l+32 the matching lo dims. shfl_xor(32) combines; lanes
// 0..31 write S hi/lo 16B frags to tiled AGG.
__global__ __launch_bounds__(256)
void spmm_k(const ushort* __restrict__ hB, const int* __restrict__ ptr,
            const int* __restrict__ srcs, const float* __restrict__ wse,
            ushort* __restrict__ AGG, int N) {
    const int node = blockIdx.x * 4 + (threadIdx.x >> 6);
    if (node >= N) return;
    const int lane = threadIdx.x & 63;
    const int p0 = ptr[node], p1 = ptr[node + 1];
    float av[8];
#pragma unroll
    for (int i = 0; i < 8; ++i) av[i] = 0.f;
    union U8 { ushort u[8]; uint4 v; };
    int j = p0;
    for (; j + 3 < p1; j += 4) {
        const int s0 = srcs[j], s1 = srcs[j + 1], s2 = srcs[j + 2], s3 = srcs[j + 3];
        const float w0 = wse[j], w1 = wse[j + 1], w2 = wse[j + 2], w3 = wse[j + 3];
        U8 u0, u1, u2, u3;
        u0.v = *(const uint4*)&hB[(size_t)s0 * 512 + lane * 8];
        u1.v = *(const uint4*)&hB[(size_t)s1 * 512 + lane * 8];
        u2.v = *(const uint4*)&hB[(size_t)s2 * 512 + lane * 8];
        u3.v = *(const uint4*)&hB[(size_t)s3 * 512 + lane * 8];
#pragma unroll
        for (int i = 0; i < 8; ++i) av[i] = fmaf(w0, bs2f(u0.u[i]), av[i]);
#pragma unroll
        for (int i = 0; i < 8; ++i) av[i] = fmaf(w1, bs2f(u1.u[i]), av[i]);
#pragma unroll
        for (int i = 0; i < 8; ++i) av[i] = fmaf(w2, bs2f(u2.u[i]), av[i]);
#pragma unroll
        for (int i = 0; i < 8; ++i) av[i] = fmaf(w3, bs2f(u3.u[i]), av[i]);
    }
    for (; j < p1; ++j) {
        const int s0 = srcs[j];
        const float w0 = wse[j];
        U8 u0;
        u0.v = *(const uint4*)&hB[(size_t)s0 * 512 + lane * 8];
#pragma unroll
        for (int i = 0; i < 8; ++i) av[i] = fmaf(w0, bs2f(u0.u[i]), av[i]);
    }
#pragma unroll
    for (int i = 0; i < 8; ++i) av[i] += __shfl_xor(av[i], 32);
    if (lane < 32) {
        const int k0 = lane * 8;
        union U8 hi8, lo8;
#pragma unroll
        for (int i = 0; i < 8; ++i) {
            const ushort hi = f2bs(av[i]);
            hi8.u[i] = hi;
            lo8.u[i] = f2bs(av[i] - bs2f(hi));
        }
        *(uint4*)&AGG[taddrA(node, k0)] = hi8.v;
        *(uint4*)&AGG[taddrA(node, 256 + k0)] = lo8.v;
    }
}

// ---------------- gates GEMM + fused GRU (R12 2-slab, proven 161.5us) -------
// A = [S hi (c0..7) | S lo (c8..15) | hH (c16..23) | hL (c24..31)], all
// TILED planes, uniform-base contiguous glds staging. B = BgA[l] for c<16,
// BgB shared for c>=16 (16 chunks each, ct-row stride 8192). BK=64: two
// BK=32 slabs per barrier pair (48KB LDS). JSKIP=3 (nh zero on S segs),
// JSKIP=2 (ni zero on h segs); lo-B only on A-hi regions (skip lo*lo).
// All skip conditions wave-uniform -> glds safe.
__global__ __launch_bounds__(256)
void gates_k(const ushort* __restrict__ AGG,
             const ushort* __restrict__ HH, const ushort* __restrict__ HL,
             const ushort* __restrict__ BgAH, const ushort* __restrict__ BgAL,
             const ushort* __restrict__ BgBH, const ushort* __restrict__ BgBL,
             const float* __restrict__ bsum, const float* __restrict__ bni,
             const float* __restrict__ bnh,
             ushort* __restrict__ HnH, ushort* __restrict__ HnL,
             const int* __restrict__ flags, int useHL, int nRB) {
    __shared__ ushort lds[24576];  // 2 slabs x (A 4096 | Bh 4096 | Bl 4096)
    const int x = blockIdx.x & 7, rem = blockIdx.x >> 3;
    const int cgB = rem & 7, rbHi = rem >> 3;
    const int rb = rbHi * 8 + x;
    if (rb >= nRB) return;
    const int tid = threadIdx.x, lane = tid & 63;
    const int wv = __builtin_amdgcn_readfirstlane(tid >> 6);
    const int wr = wv & 1, wc = wv >> 1;
    const int lm = lane & 15, lq = lane >> 4;
    const int fullsplit = !flags[0];
    const int rt = rb * 8, t0 = 2 * wv;
    f32x4 acc[4][4];
#pragma unroll
    for (int i = 0; i < 4; ++i)
#pragma unroll
        for (int j = 0; j < 4; ++j) acc[i][j] = (f32x4){0.f, 0.f, 0.f, 0.f};

// One BK=64 step = local chunks c0l, c0l+1 of B matrix {BH,BL} (NC=16).
#define GT_STEP(BH, BL, c0l, A0, ASTRIDE, JSKIP, DOLO)                         \
    do {                                                                       \
        __syncthreads();                                                       \
        GLD16((A0) + (size_t)lane * 8, &lds[t0 * 512]);                        \
        GLD16((A0) + (ASTRIDE) + (size_t)lane * 8, &lds[t0 * 512 + 512]);      \
        GLD16((A0) + 512 + (size_t)lane * 8, &lds[12288 + t0 * 512]);          \
        GLD16((A0) + (ASTRIDE) + 512 + (size_t)lane * 8, &lds[12288 + t0 * 512 + 512]); \
        const size_t bb = ((size_t)(8 * cgB + t0) * 16 + (size_t)(c0l)) * 512; \
        if ((t0 & 3) != (JSKIP)) {                                             \
            GLD16((BH) + bb + (size_t)lane * 8, &lds[4096 + t0 * 512]);        \
            GLD16((BH) + bb + 512 + (size_t)lane * 8, &lds[12288 + 4096 + t0 * 512]); \
        }                                                                      \
        if (((t0 + 1) & 3) != (JSKIP)) {                                       \
            GLD16((BH) + bb + 8192 + (size_t)lane * 8, &lds[4096 + t0 * 512 + 512]); \
            GLD16((BH) + bb + 8704 + (size_t)lane * 8, &lds[12288 + 4096 + t0 * 512 + 512]); \
        }                                                                      \
        if (DOLO) {                                                            \
            if ((t0 & 3) != (JSKIP)) {                                         \
                GLD16((BL) + bb + (size_t)lane * 8, &lds[8192 + t0 * 512]);    \
                GLD16((BL) + bb + 512 + (size_t)lane * 8, &lds[12288 + 8192 + t0 * 512]); \
            }                                                                  \
            if (((t0 + 1) & 3) != (JSKIP)) {                                   \
                GLD16((BL) + bb + 8192 + (size_t)lane * 8, &lds[8192 + t0 * 512 + 512]); \
                GLD16((BL) + bb + 8704 + (size_t)lane * 8, &lds[12288 + 8192 + t0 * 512 + 512]); \
            }                                                                  \
        }                                                                      \
        __syncthreads();                                                       \
        _Pragma("unroll")                                                      \
        for (int sb = 0; sb < 2; ++sb) {                                       \
            const int lb = sb * 12288;                                         \
            bf16x8 af[4];                                                      \
            _Pragma("unroll")                                                  \
            for (int i = 0; i < 4; ++i)                                        \
                af[i] = ldfrag(&lds[lb + (4 * wr + i) * 512 + lq * 128 + lm * 8]); \
            _Pragma("unroll")                                                  \
            for (int j = 0; j < 4; ++j) {                                      \
                if (j == (JSKIP)) continue;                                    \
                const bf16x8 bj = ldfrag(&lds[lb + 4096 + (4 * wc + j) * 512 + lq * 128 + lm * 8]); \
                _Pragma("unroll")                                              \
                for (int i = 0; i < 4; ++i) acc[i][j] = MFMA(af[i], bj, acc[i][j]); \
            }                                                                  \
            if (DOLO) {                                                        \
                _Pragma("unroll")                                              \
                for (int j = 0; j < 4; ++j) {                                  \
                    if (j == (JSKIP)) continue;                                \
                    const bf16x8 bl = ldfrag(&lds[lb + 8192 + (4 * wc + j) * 512 + lq * 128 + lm * 8]); \
                    _Pragma("unroll")                                          \
                    for (int i = 0; i < 4; ++i) acc[i][j] = MFMA(af[i], bl, acc[i][j]); \
                }                                                              \
            }                                                                  \
        }                                                                      \
    } while (0)

    // region 0: chunks 0..7   A = S hi (lo-B if fullsplit)
    for (int s = 0; s < 4; ++s) {
        const ushort* a0 = AGG + (size_t)(rt + t0) * 8192 + (size_t)(2 * s) * 512;
        GT_STEP(BgAH, BgAL, 2 * s, a0, 8192, 3, fullsplit);
    }
    // region 1: chunks 8..15  A = S lo (no lo-B: lo*lo dropped)
    for (int s = 4; s < 8; ++s) {
        const ushort* a0 = AGG + (size_t)(rt + t0) * 8192 + (size_t)(2 * s) * 512;
        GT_STEP(BgAH, BgAL, 2 * s, a0, 8192, 3, 0);
    }
    // region 2: chunks 16..23 A = hH tiled (lo-B if fullsplit)
    for (int s = 8; s < 12; ++s) {
        const ushort* a0 = HH + (size_t)(rt + t0) * 4096 + (size_t)(2 * s - 16) * 512;
        GT_STEP(BgBH, BgBL, 2 * s - 16, a0, 4096, 2, fullsplit);
    }
    // region 3: chunks 24..31 A = hL tiled (no lo-B)
    if (useHL) {
        for (int s = 12; s < 16; ++s) {
            const ushort* a0 = HL + (size_t)(rt + t0) * 4096 + (size_t)(2 * s - 24) * 512;
            GT_STEP(BgBH, BgBL, 2 * s - 16, a0, 4096, 2, 0);
        }
    }
#undef GT_STEP

    // GRU epilogue: col-tile 0..3 = r,z,ni,nh for hidden unit b
    const int b = (2 * cgB + wc) * 16 + lm;
    const float rbias = bsum[b], zbias = bsum[256 + b];
    const float ibias = bni[b], hbias = bnh[b];
#pragma unroll
    for (int i = 0; i < 4; ++i) {
        const int row0 = rb * 128 + wr * 64 + i * 16 + lq * 4;
#pragma unroll
        for (int v = 0; v < 4; ++v) {
            const int row = row0 + v;
            const size_t ho = taddrH(row, b);  // buffers padded; pads benign
            float hold = bs2f(HH[ho]);
            if (useHL) hold += bs2f(HL[ho]);
            const float r = 1.f / (1.f + expf(-(acc[i][0][v] + rbias)));
            const float z = 1.f / (1.f + expf(-(acc[i][1][v] + zbias)));
            const float nn = tanhf(acc[i][2][v] + ibias + r * (acc[i][3][v] + hbias));
            const float hv = (1.f - z) * nn + z * hold;
            const ushort hi = f2bs(hv);
            HnH[ho] = hi;
            if (useHL) HnL[ho] = f2bs(hv - bs2f(hi));
        }
    }
}

// out[n] = sum_t relu(h[n,t]) * fc_w[t] + fc_b ; one 256-thread block per node
__global__ void final_k(const ushort* __restrict__ HH, const ushort* __restrict__ HL,
                        const void* fcw, const void* fcb,
                        void* out, const int* flags, int useHL, int N) {
    const int n = blockIdx.x;
    const int t = threadIdx.x;
    const int isbf = flags[0];
    const size_t off = taddrH(n, t);
    float h = bs2f(HH[off]);
    if (useHL) h += bs2f(HL[off]);
    float v = fmaxf(h, 0.f) * ldf(fcw, t, isbf);
#pragma unroll
    for (int offx = 32; offx >= 1; offx >>= 1) v += __shfl_down(v, offx);
    __shared__ float red[4];
    if ((t & 63) == 0) red[t >> 6] = v;
    __syncthreads();
    if (t == 0) {
        const float s = red[0] + red[1] + red[2] + red[3] + ldf(fcb, 0, isbf);
        if (isbf) ((__hip_bfloat16*)out)[n] = __float2bfloat16(s);
        else      ((float*)out)[n] = s;
    }
}

extern "C" void kernel_launch(void* const* d_in, const int* in_sizes, int n_in,
                              void* d_out, int out_size, void* d_ws, size_t ws_size,
                              hipStream_t stream) {
    const int H = HDIM;
    const int N = in_sizes[0] / H;       // 50000
    const int E = in_sizes[2];           // 800000
    const int L = in_sizes[3] / (H * H); // 5
    const int NB = (N + 255) / 256;
    const int nRB = (N + 127) / 128;     // 391
    const size_t NPAD = (size_t)nRB * 128;
    const size_t hHalf = NPAD * 256;     // halves per tiled h plane
    const size_t aggHalf = NPAD * 512;

    char* p = (char*)d_ws;
    int*    flags = (int*)p;              p += 64;
    ushort* AGG  = (ushort*)p;            p += aggHalf * 2;
    ushort* HxH  = (ushort*)p;            p += hHalf * 2;
    ushort* HyH  = (ushort*)p;            p += hHalf * 2;
    ushort* hB   = (ushort*)p;            p += NPAD * 512 * 2;   // blocked plane
    float*  wihp = (float*)p;             p += (size_t)L * 768 * 256 * 4;
    ushort* BgAH = (ushort*)p;            p += (size_t)L * 524288 * 2;
    ushort* BgAL = (ushort*)p;            p += (size_t)L * 524288 * 2;
    ushort* BgBH = (ushort*)p;            p += (size_t)524288 * 2;
    ushort* BgBL = (ushort*)p;            p += (size_t)524288 * 2;
    float*  bsum = (float*)p;             p += 512 * 4;
    float*  bni  = (float*)p;             p += 256 * 4;
    float*  bnh  = (float*)p;             p += 256 * 4;
    int*    ptr  = (int*)p;               p += (size_t)(N + 1) * 4;
    int*    cursor = (int*)p;             p += (size_t)N * 4;
    int*    bsumN  = (int*)p;             p += (size_t)NB * 4;
    int*    srcs   = (int*)p;             p += (size_t)E * 4;
    float*  wse    = (float*)p;           p += (size_t)E * 4;
    const size_t need_reduced = (size_t)(p - (char*)d_ws);
    ushort* HxL = (ushort*)p;             // optional hi/lo tiled h planes
    ushort* HyL = (ushort*)(p + hHalf * 2);
    const size_t need_full = need_reduced + 2 * hHalf * 2;
    const int useHL = (ws_size >= need_full) ? 1 : 0;
    if (!useHL) { HxL = HxH; HyL = HyH; }  // never dereferenced when useHL=0

    detect_k<<<dim3(1), dim3(64), 0, stream>>>(d_in[0], d_in[1], flags);
    conv_h0_k<<<dim3((unsigned)NPAD), dim3(256), 0, stream>>>(
        d_in[0], HxH, HxL, hB, flags, useHL, N, NPAD * 256);
    prep1_k<<<dim3((unsigned)(L * 768)), dim3(256), 0, stream>>>(
        d_in[4], d_in[3], wihp, flags);
    prep2_k<<<dim3((unsigned)(L * 2048)), dim3(256), 0, stream>>>(
        wihp, d_in[5], d_in[6], d_in[7],
        BgAH, BgAL, BgBH, BgBL, bsum, bni, bnh, flags, L);

    zero_int_k<<<dim3(NB), dim3(256), 0, stream>>>(cursor, N);
    count_k<<<dim3((E + 255) / 256), dim3(256), 0, stream>>>(d_in[1], cursor, flags, E);
    scan1_k<<<dim3(NB), dim3(256), 0, stream>>>(cursor, ptr, bsumN, N);
    scan2_k<<<dim3(1), dim3(256), 0, stream>>>(bsumN, NB);
    scan3_k<<<dim3(NB), dim3(256), 0, stream>>>(ptr, cursor, bsumN, N, E);
    fill_k<<<dim3((E + 255) / 256), dim3(256), 0, stream>>>(
        d_in[1], d_in[2], cursor, srcs, wse, flags, E);

    const dim3 blk(256);
    const unsigned gGrid = 64u * (unsigned)((nRB + 7) / 8);
    const int ngroups = (int)(NPAD * 32);      // fragments per plane
    const unsigned rGrid = (unsigned)((ngroups + 255) / 256);
    ushort *HcH = HxH, *HcL = HxL, *HnH = HyH, *HnL = HyL;
    for (int l = 0; l < L; ++l) {
        spmm_k<<<dim3((N + 3) / 4), blk, 0, stream>>>(hB, ptr, srcs, wse, AGG, N);
        gates_k<<<dim3(gGrid), blk, 0, stream>>>(
            AGG, HcH, HcL,
            BgAH + (size_t)l * 524288, BgAL + (size_t)l * 524288,
            BgBH, BgBL, bsum, bni, bnh, HnH, HnL, flags, useHL, nRB);
        if (l + 1 < L)
            repack_k<<<dim3(rGrid), blk, 0, stream>>>(HnH, HnL, hB, useHL, ngroups);
        ushort* t;
        t = HcH; HcH = HnH; HnH = t;
        t = HcL; HcL = HnL; HnL = t;
    }
    final_k<<<dim3(N), blk, 0, stream>>>(
        HcH, HcL, d_in[8], d_in[9], d_out, flags, useHL, N);
}

// Round 11
// 1913.333 us; speedup vs baseline: 1.0752x; 1.0062x over previous
//
#include <hip/hip_runtime.h>
#include <hip/hip_bf16.h>
#include <math.h>

// GGNN: L=5 layers of { m = h@W_l ; agg = scatter_add(ew * m[src] -> dst) ;
//                       h = GRUCell(agg, h) } then out = relu(h)@fc_w^T + fc_b
// H=256, N=50000, E=800000.
//
// R15: weight folding deleted m_gemm. R17/R18: dual-layout h (tiled for
// gates staging, blocked hB for spmm gather) + repack kernel. R19 counted
// vmcnt regressed (reverted); R20 = R12 2-slab gates (160us x4 confirmed)
// + spmm unroll-4.
// R21 (this round): gates tile 128x128 -> 128x256 (8 waves 2x4, 512 thr).
//   A panel staged 4x instead of 8x (-400MB/dispatch staging); schedule,
//   fragment addressing, skip logic, epilogue form UNCHANGED (parameter
//   change only). LDS 80KB -> 2 blocks/CU = 16 waves/CU (4/SIMD, more TLP
//   than before). Per-wave work identical (576 MFMA).

#define HDIM 256

using bf16x8 = __attribute__((ext_vector_type(8))) short;
using f32x4  = __attribute__((ext_vector_type(4))) float;

__device__ __forceinline__ bf16x8 ldfrag(const ushort* p) {
    union { uint4 u; bf16x8 f; } x;
    x.u = *(const uint4*)p;
    return x.f;
}
#define MFMA(a, b, c) __builtin_amdgcn_mfma_f32_16x16x32_bf16((a), (b), (c), 0, 0, 0)
#define GLD16(g, l)                                                            \
    __builtin_amdgcn_global_load_lds(                                          \
        (const __attribute__((address_space(1))) void*)(g),                    \
        (__attribute__((address_space(3))) void*)(l), 16, 0, 0)

__device__ __forceinline__ float ldf(const void* p, size_t i, int isbf) {
    if (isbf) return __bfloat162float(((const __hip_bfloat16*)p)[i]);
    return ((const float*)p)[i];
}
__device__ __forceinline__ ushort f2bs(float v) {
    __hip_bfloat16 b = __float2bfloat16(v);
    return *(ushort*)&b;
}
__device__ __forceinline__ float bs2f(ushort u) {
    __hip_bfloat16 b = *(__hip_bfloat16*)&u;
    return __bfloat162float(b);
}
// tiled plane addr, K-extent 256 (h planes): 16x32 fragment tiles of 512 halves
__device__ __forceinline__ size_t taddrH(int n, int k) {
    return (size_t)(n >> 4) * 4096 + (size_t)((k >> 5) << 9)
         + (size_t)(((k >> 3) & 3) << 7) + (size_t)((n & 15) << 3) + (k & 7);
}
// tiled plane addr, K-extent 512 (S hi|lo combined) — AGG only
__device__ __forceinline__ size_t taddrA(int n, int k) {
    return (size_t)(n >> 4) * 8192 + (size_t)((k >> 5) << 9)
         + (size_t)(((k >> 3) & 3) << 7) + (size_t)((n & 15) << 3) + (k & 7);
}

// flags[0] = 1 if float tensors are bf16, 0 if f32
// flags[1] = 1 if edge_index is int64, 0 if int32
__global__ void detect_k(const void* x, const void* ei, int* flags) {
    if (blockIdx.x == 0 && threadIdx.x == 0) {
        const __hip_bfloat16* xb = (const __hip_bfloat16*)x;
        int isbf = 1;
        for (int i = 0; i < 1024; ++i) {
            float v = fabsf(__bfloat162float(xb[i]));
            if (!(v < 1e6f)) { isbf = 0; break; }
        }
        flags[0] = isbf;
        const int* e32 = (const int*)ei;
        int orv = e32[1] | e32[3] | e32[5] | e32[7] | e32[9] | e32[11];
        flags[1] = (orv == 0) ? 1 : 0;
    }
}

// x -> tiled h planes + blocked hB plane; pad rows zeroed
__global__ void conv_h0_k(const void* x, ushort* HH, ushort* HL, ushort* hB,
                          const int* flags, int useHL, int Nn, size_t npad256) {
    size_t i = (size_t)blockIdx.x * blockDim.x + threadIdx.x;
    if (i >= npad256) return;
    const int n = (int)(i >> 8), k = (int)(i & 255);
    float v = 0.f;
    if (n < Nn) v = ldf(x, i, flags[0]);
    const ushort hi = f2bs(v);
    const ushort lo = f2bs(v - bs2f(hi));
    const size_t a = taddrH(n, k);
    HH[a] = hi;
    if (useHL) HL[a] = lo;
    hB[(size_t)n * 512 + k] = hi;
    hB[(size_t)n * 512 + 256 + k] = lo;
}

// tiled h planes -> blocked hB. Each thread moves one 8-half fragment (16B)
// of hi + the matching lo.
__global__ void repack_k(const ushort* __restrict__ TH, const ushort* __restrict__ TL,
                         ushort* __restrict__ hB, int useHL, int ngroups) {
    const int g = blockIdx.x * 256 + threadIdx.x;
    if (g >= ngroups) return;
    const int t = g >> 9, o = (g & 511) * 8;
    const int k = ((o >> 9) << 5) | (((o >> 7) & 3) << 3);
    const int n = t * 16 + ((o >> 3) & 15);
    const uint4 hv = *(const uint4*)&TH[(size_t)t * 4096 + o];
    *(uint4*)&hB[(size_t)n * 512 + k] = hv;
    uint4 lv;
    if (useHL) lv = *(const uint4*)&TL[(size_t)t * 4096 + o];
    else       lv = make_uint4(0u, 0u, 0u, 0u);
    *(uint4*)&hB[(size_t)n * 512 + 256 + k] = lv;
}

// WihP[l][r][k] = sum_j Wih[r][j] * W[l][k][j]  (f32, 16x16-tiled, LDS-staged)
__global__ __launch_bounds__(256)
void prep1_k(const void* wih, const void* w, float* wihp, const int* flags) {
    __shared__ float As[16][260], Bs[16][260];
    const int bx = blockIdx.x;            // l*768 + rt16*16 + kt16
    const int l = bx / 768, rem = bx % 768;
    const int rt = (rem >> 4) << 4, kt = (rem & 15) << 4;
    const int tid = threadIdx.x, isbf = flags[0];
    for (int idx = tid; idx < 4096; idx += 256) {
        const int row = idx >> 8, col = idx & 255;
        As[row][col] = ldf(wih, (size_t)(rt + row) * 256 + col, isbf);
        Bs[row][col] = ldf(w, (size_t)l * 65536 + (size_t)(kt + row) * 256 + col, isbf);
    }
    __syncthreads();
    const int ri = tid >> 4, ki = tid & 15;
    float acc = 0.f;
    for (int j = 0; j < 256; ++j) acc = fmaf(As[ri][j], Bs[ki][j], acc);
    wihp[((size_t)l * 768 + rt + ri) * 256 + kt + ki] = acc;
}

// Build tiled gate-B matrices + biases.
// BgA[l] [1024 out][512 k] (k segs = S hi / S lo), out col j: g=(j>>4)&3,
//   b=16*(j>>6)+(j&15): g in {r,z,ni}: WihP[l][g*256+b][kk]; nh: 0.
// BgB (shared) [1024 out][512 k] (k segs = h hi / h lo): g in {r,z}:
//   Whh[g*256+b][kk]; nh: Whh[512+b][kk]; ni: 0.
__global__ void prep2_k(const float* __restrict__ wihp, const void* whh,
                        const void* bih, const void* bhh,
                        ushort* BgAH, ushort* BgAL, ushort* BgBH, ushort* BgBL,
                        float* bsum, float* bni, float* bnh,
                        const int* flags, int L) {
    const int i = blockIdx.x * blockDim.x + threadIdx.x;
    const int isbf = flags[0];
    if (i < (L << 19)) {
        const int l = i >> 19, r2 = i & 524287;
        const int j = r2 >> 9, k = r2 & 511;
        const int g = (j >> 4) & 3, b = ((j >> 6) << 4) + (j & 15);
        const int kk = k & 255;
        const float v = (g == 3) ? 0.f
                      : wihp[((size_t)l * 768 + g * 256 + b) * 256 + kk];
        const ushort hi = f2bs(v);
        const int ct = j >> 4, c = k >> 5;
        const size_t a = (size_t)l * 524288 + (size_t)(ct * 16 + c) * 512
                       + (size_t)(((k >> 3) & 3) << 7) + ((j & 15) << 3) + (k & 7);
        BgAH[a] = hi; BgAL[a] = f2bs(v - bs2f(hi));
    }
    if (i < 524288) {
        const int j = i >> 9, k = i & 511;
        const int g = (j >> 4) & 3, b = ((j >> 6) << 4) + (j & 15);
        const int kk = k & 255;
        float v;
        if (g == 0)      v = ldf(whh, (size_t)b * 256 + kk, isbf);
        else if (g == 1) v = ldf(whh, (size_t)(256 + b) * 256 + kk, isbf);
        else if (g == 2) v = 0.f;
        else             v = ldf(whh, (size_t)(512 + b) * 256 + kk, isbf);
        const ushort hi = f2bs(v);
        const int ct = j >> 4, c = k >> 5;
        const size_t a = (size_t)(ct * 16 + c) * 512
                       + (size_t)(((k >> 3) & 3) << 7) + ((j & 15) << 3) + (k & 7);
        BgBH[a] = hi; BgBL[a] = f2bs(v - bs2f(hi));
    }
    if (i < 512) bsum[i] = ldf(bih, i, isbf) + ldf(bhh, i, isbf);
    if (i < 256) {
        bni[i] = ldf(bih, 512 + i, isbf);
        bnh[i] = ldf(bhh, 512 + i, isbf);
    }
}

// ---------------- CSR build (by dst), once per call ----------------

__global__ void zero_int_k(int* p, int n) {
    int i = blockIdx.x * blockDim.x + threadIdx.x;
    if (i < n) p[i] = 0;
}

__global__ void count_k(const void* ei, int* cnt, const int* flags, int E) {
    int e = blockIdx.x * blockDim.x + threadIdx.x;
    if (e >= E) return;
    const int* e32 = (const int*)ei;
    int d = flags[1] ? e32[2 * ((size_t)E + e)] : e32[(size_t)E + e];
    atomicAdd(&cnt[d], 1);
}

__global__ __launch_bounds__(256)
void scan1_k(const int* cnt, int* ptr, int* bsumN, int N) {
    __shared__ int s[256];
    const int t = threadIdx.x;
    const int gid = blockIdx.x * 256 + t;
    int v = (gid < N) ? cnt[gid] : 0;
    const int own = v;
    s[t] = v;
    __syncthreads();
#pragma unroll
    for (int off = 1; off < 256; off <<= 1) {
        int add = (t >= off) ? s[t - off] : 0;
        __syncthreads();
        s[t] += add;
        __syncthreads();
    }
    if (gid < N) ptr[gid] = s[t] - own;
    if (t == 255) bsumN[blockIdx.x] = s[255];
}

__global__ __launch_bounds__(256)
void scan2_k(int* bsumN, int NB) {
    __shared__ int s[256];
    __shared__ int carry;
    const int t = threadIdx.x;
    if (t == 0) carry = 0;
    __syncthreads();
    for (int base = 0; base < NB; base += 256) {
        const int i = base + t;
        int v = (i < NB) ? bsumN[i] : 0;
        const int own = v;
        s[t] = v;
        __syncthreads();
#pragma unroll
        for (int off = 1; off < 256; off <<= 1) {
            int add = (t >= off) ? s[t - off] : 0;
            __syncthreads();
            s[t] += add;
            __syncthreads();
        }
        if (i < NB) bsumN[i] = carry + s[t] - own;
        __syncthreads();
        if (t == 0) carry += s[255];
        __syncthreads();
    }
}

__global__ void scan3_k(int* ptr, int* cursor, const int* bsumN, int N, int E) {
    const int gid = blockIdx.x * 256 + threadIdx.x;
    if (gid < N) {
        const int p = ptr[gid] + bsumN[blockIdx.x];
        ptr[gid] = p;
        cursor[gid] = p;
    }
    if (gid == 0) ptr[N] = E;
}

__global__ void fill_k(const void* ei, const void* ew, int* cursor,
                       int* srcs, float* wse, const int* flags, int E) {
    int e = blockIdx.x * blockDim.x + threadIdx.x;
    if (e >= E) return;
    const int* e32 = (const int*)ei;
    int s, d;
    if (flags[1]) { s = e32[2 * (size_t)e]; d = e32[2 * ((size_t)E + e)]; }
    else          { s = e32[e];             d = e32[(size_t)E + e]; }
    const int p = atomicAdd(&cursor[d], 1);
    srcs[p] = s;
    wse[p] = ldf(ew, e, flags[0]);
}

// ---------------- SpMM gather: S[d] = sum_j w_j * h[src_j] ------------------
// hB blocked [n][512] (hi row | lo row): ONE 16B load per lane per edge.
// unroll-4: four independent gather loads in flight before any FMA.
__global__ __launch_bounds__(256)
void spmm_k(const ushort* __restrict__ hB, const int* __restrict__ ptr,
            const int* __restrict__ srcs, const float* __restrict__ wse,
            ushort* __restrict__ AGG, int N) {
    const int node = blockIdx.x * 4 + (threadIdx.x >> 6);
    if (node >= N) return;
    const int lane = threadIdx.x & 63;
    const int p0 = ptr[node], p1 = ptr[node + 1];
    float av[8];
#pragma unroll
    for (int i = 0; i < 8; ++i) av[i] = 0.f;
    union U8 { ushort u[8]; uint4 v; };
    int j = p0;
    for (; j + 3 < p1; j += 4) {
        const int s0 = srcs[j], s1 = srcs[j + 1], s2 = srcs[j + 2], s3 = srcs[j + 3];
        const float w0 = wse[j], w1 = wse[j + 1], w2 = wse[j + 2], w3 = wse[j + 3];
        U8 u0, u1, u2, u3;
        u0.v = *(const uint4*)&hB[(size_t)s0 * 512 + lane * 8];
        u1.v = *(const uint4*)&hB[(size_t)s1 * 512 + lane * 8];
        u2.v = *(const uint4*)&hB[(size_t)s2 * 512 + lane * 8];
        u3.v = *(const uint4*)&hB[(size_t)s3 * 512 + lane * 8];
#pragma unroll
        for (int i = 0; i < 8; ++i) av[i] = fmaf(w0, bs2f(u0.u[i]), av[i]);
#pragma unroll
        for (int i = 0; i < 8; ++i) av[i] = fmaf(w1, bs2f(u1.u[i]), av[i]);
#pragma unroll
        for (int i = 0; i < 8; ++i) av[i] = fmaf(w2, bs2f(u2.u[i]), av[i]);
#pragma unroll
        for (int i = 0; i < 8; ++i) av[i] = fmaf(w3, bs2f(u3.u[i]), av[i]);
    }
    for (; j < p1; ++j) {
        const int s0 = srcs[j];
        const float w0 = wse[j];
        U8 u0;
        u0.v = *(const uint4*)&hB[(size_t)s0 * 512 + lane * 8];
#pragma unroll
        for (int i = 0; i < 8; ++i) av[i] = fmaf(w0, bs2f(u0.u[i]), av[i]);
    }
#pragma unroll
    for (int i = 0; i < 8; ++i) av[i] += __shfl_xor(av[i], 32);
    if (lane < 32) {
        const int k0 = lane * 8;
        union U8 hi8, lo8;
#pragma unroll
        for (int i = 0; i < 8; ++i) {
            const ushort hi = f2bs(av[i]);
            hi8.u[i] = hi;
            lo8.u[i] = f2bs(av[i] - bs2f(hi));
        }
        *(uint4*)&AGG[taddrA(node, k0)] = hi8.v;
        *(uint4*)&AGG[taddrA(node, 256 + k0)] = lo8.v;
    }
}

// ---------------- gates GEMM + fused GRU (128x256 tile, 8 waves) ------------
// R21 geometry: BM=128, BN=256, 8 waves (wr=wv&1 rows, wc=wv>>1 cols),
// 512 threads. Same BK=64 2-slab full-drain schedule as the proven R12 form;
// each wave does the identical 576-MFMA workload with identical fragment
// addressing. A staged once per (row-block, cgB) with cgB in {0..3}
// (was {0..7}) -> A staging traffic halves. LDS 80KB (2 slabs x
// (A 4096 | Bh 8192 | Bl 8192) halves), 2 blocks/CU = 4 waves/SIMD.
// A = [S hi (c0..7) | S lo (c8..15) | hH (c16..23) | hL (c24..31)].
// B = BgA[l] for c<16, BgB shared for c>=16. JSKIP=3 (nh zero on S segs),
// JSKIP=2 (ni zero on h segs); lo-B only on A-hi regions. Wave-uniform.
__global__ __launch_bounds__(512)
void gates_k(const ushort* __restrict__ AGG,
             const ushort* __restrict__ HH, const ushort* __restrict__ HL,
             const ushort* __restrict__ BgAH, const ushort* __restrict__ BgAL,
             const ushort* __restrict__ BgBH, const ushort* __restrict__ BgBL,
             const float* __restrict__ bsum, const float* __restrict__ bni,
             const float* __restrict__ bnh,
             ushort* __restrict__ HnH, ushort* __restrict__ HnL,
             const int* __restrict__ flags, int useHL, int nRB) {
    __shared__ ushort lds[40960];  // 2 slabs x (A 4096 | Bh 8192 | Bl 8192)
    const int x = blockIdx.x & 7, rem = blockIdx.x >> 3;
    const int cgB = rem & 3, rbHi = rem >> 2;
    const int rb = rbHi * 8 + x;
    if (rb >= nRB) return;
    const int tid = threadIdx.x, lane = tid & 63;
    const int wv = __builtin_amdgcn_readfirstlane(tid >> 6);  // 0..7
    const int wr = wv & 1, wc = wv >> 1;                      // 2 x 4 waves
    const int lm = lane & 15, lq = lane >> 4;
    const int fullsplit = !flags[0];
    const int rt = rb * 8, t0 = 2 * wv;  // t0: local B col-tile base (0..14)
    f32x4 acc[4][4];
#pragma unroll
    for (int i = 0; i < 4; ++i)
#pragma unroll
        for (int j = 0; j < 4; ++j) acc[i][j] = (f32x4){0.f, 0.f, 0.f, 0.f};

// One BK=64 step = chunks c0l, c0l+1 of B matrix {BH,BL} (NC=16 each).
// A0: this wave's A tile-row (rt+wv) at chunk c0l (chunk stride 512 both
// planes). Wave stages: A slab0/slab1 (1 GLD each) + its 2 B col-strips.
#define GT_STEP(BH, BL, c0l, A0, JSKIP, DOLO)                                  \
    do {                                                                       \
        __syncthreads();                                                       \
        GLD16((A0) + (size_t)lane * 8, &lds[wv * 512]);                        \
        GLD16((A0) + 512 + (size_t)lane * 8, &lds[20480 + wv * 512]);          \
        const size_t bb = ((size_t)(16 * cgB + t0) * 16 + (size_t)(c0l)) * 512; \
        if ((t0 & 3) != (JSKIP)) {                                             \
            GLD16((BH) + bb + (size_t)lane * 8, &lds[4096 + t0 * 512]);        \
            GLD16((BH) + bb + 512 + (size_t)lane * 8, &lds[20480 + 4096 + t0 * 512]); \
        }                                                                      \
        if (((t0 + 1) & 3) != (JSKIP)) {                                       \
            GLD16((BH) + bb + 8192 + (size_t)lane * 8, &lds[4096 + (t0 + 1) * 512]); \
            GLD16((BH) + bb + 8704 + (size_t)lane * 8, &lds[20480 + 4096 + (t0 + 1) * 512]); \
        }                                                                      \
        if (DOLO) {                                                            \
            if ((t0 & 3) != (JSKIP)) {                                         \
                GLD16((BL) + bb + (size_t)lane * 8, &lds[12288 + t0 * 512]);   \
                GLD16((BL) + bb + 512 + (size_t)lane * 8, &lds[20480 + 12288 + t0 * 512]); \
            }                                                                  \
            if (((t0 + 1) & 3) != (JSKIP)) {                                   \
                GLD16((BL) + bb + 8192 + (size_t)lane * 8, &lds[12288 + (t0 + 1) * 512]); \
                GLD16((BL) + bb + 8704 + (size_t)lane * 8, &lds[20480 + 12288 + (t0 + 1) * 512]); \
            }                                                                  \
        }                                                                      \
        __syncthreads();                                                       \
        _Pragma("unroll")                                                      \
        for (int sb = 0; sb < 2; ++sb) {                                       \
            const int lb = sb * 20480;                                         \
            bf16x8 af[4];                                                      \
            _Pragma("unroll")                                                  \
            for (int i = 0; i < 4; ++i)                                        \
                af[i] = ldfrag(&lds[lb + (4 * wr + i) * 512 + lq * 128 + lm * 8]); \
            _Pragma("unroll")                                                  \
            for (int j = 0; j < 4; ++j) {                                      \
                if (j == (JSKIP)) continue;                                    \
                const bf16x8 bj = ldfrag(&lds[lb + 4096 + (4 * wc + j) * 512 + lq * 128 + lm * 8]); \
                _Pragma("unroll")                                              \
                for (int i = 0; i < 4; ++i) acc[i][j] = MFMA(af[i], bj, acc[i][j]); \
            }                                                                  \
            if (DOLO) {                                                        \
                _Pragma("unroll")                                              \
                for (int j = 0; j < 4; ++j) {                                  \
                    if (j == (JSKIP)) continue;                                \
                    const bf16x8 bl = ldfrag(&lds[lb + 12288 + (4 * wc + j) * 512 + lq * 128 + lm * 8]); \
                    _Pragma("unroll")                                          \
                    for (int i = 0; i < 4; ++i) acc[i][j] = MFMA(af[i], bl, acc[i][j]); \
                }                                                              \
            }                                                                  \
        }                                                                      \
    } while (0)

    // region 0: chunks 0..7   A = S hi (lo-B if fullsplit)
    for (int s = 0; s < 4; ++s) {
        const ushort* a0 = AGG + (size_t)(rt + wv) * 8192 + (size_t)(2 * s) * 512;
        GT_STEP(BgAH, BgAL, 2 * s, a0, 3, fullsplit);
    }
    // region 1: chunks 8..15  A = S lo (no lo-B: lo*lo dropped)
    for (int s = 4; s < 8; ++s) {
        const ushort* a0 = AGG + (size_t)(rt + wv) * 8192 + (size_t)(2 * s) * 512;
        GT_STEP(BgAH, BgAL, 2 * s, a0, 3, 0);
    }
    // region 2: chunks 16..23 A = hH tiled (lo-B if fullsplit)
    for (int s = 8; s < 12; ++s) {
        const ushort* a0 = HH + (size_t)(rt + wv) * 4096 + (size_t)(2 * s - 16) * 512;
        GT_STEP(BgBH, BgBL, 2 * s - 16, a0, 2, fullsplit);
    }
    // region 3: chunks 24..31 A = hL tiled (no lo-B)
    if (useHL) {
        for (int s = 12; s < 16; ++s) {
            const ushort* a0 = HL + (size_t)(rt + wv) * 4096 + (size_t)(2 * s - 24) * 512;
            GT_STEP(BgBH, BgBL, 2 * s - 16, a0, 2, 0);
        }
    }
#undef GT_STEP

    // GRU epilogue: col-tile 0..3 = r,z,ni,nh for hidden unit b
    const int b = (4 * cgB + wc) * 16 + lm;
    const float rbias = bsum[b], zbias = bsum[256 + b];
    const float ibias = bni[b], hbias = bnh[b];
#pragma unroll
    for (int i = 0; i < 4; ++i) {
        const int row0 = rb * 128 + wr * 64 + i * 16 + lq * 4;
#pragma unroll
        for (int v = 0; v < 4; ++v) {
            const int row = row0 + v;
            const size_t ho = taddrH(row, b);  // buffers padded; pads benign
            float hold = bs2f(HH[ho]);
            if (useHL) hold += bs2f(HL[ho]);
            const float r = 1.f / (1.f + expf(-(acc[i][0][v] + rbias)));
            const float z = 1.f / (1.f + expf(-(acc[i][1][v] + zbias)));
            const float nn = tanhf(acc[i][2][v] + ibias + r * (acc[i][3][v] + hbias));
            const float hv = (1.f - z) * nn + z * hold;
            const ushort hi = f2bs(hv);
            HnH[ho] = hi;
            if (useHL) HnL[ho] = f2bs(hv - bs2f(hi));
        }
    }
}

// out[n] = sum_t relu(h[n,t]) * fc_w[t] + fc_b ; one 256-thread block per node
__global__ void final_k(const ushort* __restrict__ HH, const ushort* __restrict__ HL,
                        const void* fcw, const void* fcb,
                        void* out, const int* flags, int useHL, int N) {
    const int n = blockIdx.x;
    const int t = threadIdx.x;
    const int isbf = flags[0];
    const size_t off = taddrH(n, t);
    float h = bs2f(HH[off]);
    if (useHL) h += bs2f(HL[off]);
    float v = fmaxf(h, 0.f) * ldf(fcw, t, isbf);
#pragma unroll
    for (int offx = 32; offx >= 1; offx >>= 1) v += __shfl_down(v, offx);
    __shared__ float red[4];
    if ((t & 63) == 0) red[t >> 6] = v;
    __syncthreads();
    if (t == 0) {
        const float s = red[0] + red[1] + red[2] + red[3] + ldf(fcb, 0, isbf);
        if (isbf) ((__hip_bfloat16*)out)[n] = __float2bfloat16(s);
        else      ((float*)out)[n] = s;
    }
}

extern "C" void kernel_launch(void* const* d_in, const int* in_sizes, int n_in,
                              void* d_out, int out_size, void* d_ws, size_t ws_size,
                              hipStream_t stream) {
    const int H = HDIM;
    const int N = in_sizes[0] / H;       // 50000
    const int E = in_sizes[2];           // 800000
    const int L = in_sizes[3] / (H * H); // 5
    const int NB = (N + 255) / 256;
    const int nRB = (N + 127) / 128;     // 391
    const size_t NPAD = (size_t)nRB * 128;
    const size_t hHalf = NPAD * 256;     // halves per tiled h plane
    const size_t aggHalf = NPAD * 512;

    char* p = (char*)d_ws;
    int*    flags = (int*)p;              p += 64;
    ushort* AGG  = (ushort*)p;            p += aggHalf * 2;
    ushort* HxH  = (ushort*)p;            p += hHalf * 2;
    ushort* HyH  = (ushort*)p;            p += hHalf * 2;
    ushort* hB   = (ushort*)p;            p += NPAD * 512 * 2;   // blocked plane
    float*  wihp = (float*)p;             p += (size_t)L * 768 * 256 * 4;
    ushort* BgAH = (ushort*)p;            p += (size_t)L * 524288 * 2;
    ushort* BgAL = (ushort*)p;            p += (size_t)L * 524288 * 2;
    ushort* BgBH = (ushort*)p;            p += (size_t)524288 * 2;
    ushort* BgBL = (ushort*)p;            p += (size_t)524288 * 2;
    float*  bsum = (float*)p;             p += 512 * 4;
    float*  bni  = (float*)p;             p += 256 * 4;
    float*  bnh  = (float*)p;             p += 256 * 4;
    int*    ptr  = (int*)p;               p += (size_t)(N + 1) * 4;
    int*    cursor = (int*)p;             p += (size_t)N * 4;
    int*    bsumN  = (int*)p;             p += (size_t)NB * 4;
    int*    srcs   = (int*)p;             p += (size_t)E * 4;
    float*  wse    = (float*)p;           p += (size_t)E * 4;
    const size_t need_reduced = (size_t)(p - (char*)d_ws);
    ushort* HxL = (ushort*)p;             // optional hi/lo tiled h planes
    ushort* HyL = (ushort*)(p + hHalf * 2);
    const size_t need_full = need_reduced + 2 * hHalf * 2;
    const int useHL = (ws_size >= need_full) ? 1 : 0;
    if (!useHL) { HxL = HxH; HyL = HyH; }  // never dereferenced when useHL=0

    detect_k<<<dim3(1), dim3(64), 0, stream>>>(d_in[0], d_in[1], flags);
    conv_h0_k<<<dim3((unsigned)NPAD), dim3(256), 0, stream>>>(
        d_in[0], HxH, HxL, hB, flags, useHL, N, NPAD * 256);
    prep1_k<<<dim3((unsigned)(L * 768)), dim3(256), 0, stream>>>(
        d_in[4], d_in[3], wihp, flags);
    prep2_k<<<dim3((unsigned)(L * 2048)), dim3(256), 0, stream>>>(
        wihp, d_in[5], d_in[6], d_in[7],
        BgAH, BgAL, BgBH, BgBL, bsum, bni, bnh, flags, L);

    zero_int_k<<<dim3(NB), dim3(256), 0, stream>>>(cursor, N);
    count_k<<<dim3((E + 255) / 256), dim3(256), 0, stream>>>(d_in[1], cursor, flags, E);
    scan1_k<<<dim3(NB), dim3(256), 0, stream>>>(cursor, ptr, bsumN, N);
    scan2_k<<<dim3(1), dim3(256), 0, stream>>>(bsumN, NB);
    scan3_k<<<dim3(NB), dim3(256), 0, stream>>>(ptr, cursor, bsumN, N, E);
    fill_k<<<dim3((E + 255) / 256), dim3(256), 0, stream>>>(
        d_in[1], d_in[2], cursor, srcs, wse, flags, E);

    const dim3 blk(256);
    const unsigned gGrid = 32u * (unsigned)((nRB + 7) / 8);  // 8(x) x 4(cgB)
    const int ngroups = (int)(NPAD * 32);      // fragments per plane
    const unsigned rGrid = (unsigned)((ngroups + 255) / 256);
    ushort *HcH = HxH, *HcL = HxL, *HnH = HyH, *HnL = HyL;
    for (int l = 0; l < L; ++l) {
        spmm_k<<<dim3((N + 3) / 4), blk, 0, stream>>>(hB, ptr, srcs, wse, AGG, N);
        gates_k<<<dim3(gGrid), dim3(512), 0, stream>>>(
            AGG, HcH, HcL,
            BgAH + (size_t)l * 524288, BgAL + (size_t)l * 524288,
            BgBH, BgBL, bsum, bni, bnh, HnH, HnL, flags, useHL, nRB);
        if (l + 1 < L)
            repack_k<<<dim3(rGrid), blk, 0, stream>>>(HnH, HnL, hB, useHL, ngroups);
        ushort* t;
        t = HcH; HcH = HnH; HnH = t;
        t = HcL; HcL = HnL; HnL = t;
    }
    final_k<<<dim3(N), blk, 0, stream>>>(
        HcH, HcL, d_in[8], d_in[9], d_out, flags, useHL, N);
}

// Round 12
// 1906.865 us; speedup vs baseline: 1.0788x; 1.0034x over previous
//
#include <hip/hip_runtime.h>
#include <hip/hip_bf16.h>
#include <math.h>

// GGNN: L=5 layers of { m = h@W_l ; agg = scatter_add(ew * m[src] -> dst) ;
//                       h = GRUCell(agg, h) } then out = relu(h)@fc_w^T + fc_b
// H=256, N=50000, E=800000.
//
// R15: weight folding deleted m_gemm. R17/R18: dual-layout h (tiled for
// gates staging, blocked hB for spmm gather) + repack kernel.
// R19 counted-vmcnt: regressed. R21 128x256 tile: +4us (gates is
// drain-latency-bound, not staging-BW-bound). Both reverted.
// R22 (this round): gates_k = R20/R12 2-slab 128x128 (160.5us, x4 proven).
//   detect_k: serial 1024-iter single-lane loop -> 64-lane + __ballot
//   (~25us -> ~1us). final_k: wave-per-node (4 nodes/block, ushort4 col
//   read, pure shfl reduce; 12500 blocks vs 50000, no LDS/sync).

#define HDIM 256

using bf16x8 = __attribute__((ext_vector_type(8))) short;
using f32x4  = __attribute__((ext_vector_type(4))) float;

__device__ __forceinline__ bf16x8 ldfrag(const ushort* p) {
    union { uint4 u; bf16x8 f; } x;
    x.u = *(const uint4*)p;
    return x.f;
}
#define MFMA(a, b, c) __builtin_amdgcn_mfma_f32_16x16x32_bf16((a), (b), (c), 0, 0, 0)
#define GLD16(g, l)                                                            \
    __builtin_amdgcn_global_load_lds(                                          \
        (const __attribute__((address_space(1))) void*)(g),                    \
        (__attribute__((address_space(3))) void*)(l), 16, 0, 0)

__device__ __forceinline__ float ldf(const void* p, size_t i, int isbf) {
    if (isbf) return __bfloat162float(((const __hip_bfloat16*)p)[i]);
    return ((const float*)p)[i];
}
__device__ __forceinline__ ushort f2bs(float v) {
    __hip_bfloat16 b = __float2bfloat16(v);
    return *(ushort*)&b;
}
__device__ __forceinline__ float bs2f(ushort u) {
    __hip_bfloat16 b = *(__hip_bfloat16*)&u;
    return __bfloat162float(b);
}
// tiled plane addr, K-extent 256 (h planes): 16x32 fragment tiles of 512 halves
__device__ __forceinline__ size_t taddrH(int n, int k) {
    return (size_t)(n >> 4) * 4096 + (size_t)((k >> 5) << 9)
         + (size_t)(((k >> 3) & 3) << 7) + (size_t)((n & 15) << 3) + (k & 7);
}
// tiled plane addr, K-extent 512 (S hi|lo combined) — AGG only
__device__ __forceinline__ size_t taddrA(int n, int k) {
    return (size_t)(n >> 4) * 8192 + (size_t)((k >> 5) << 9)
         + (size_t)(((k >> 3) & 3) << 7) + (size_t)((n & 15) << 3) + (k & 7);
}

// flags[0] = 1 if float tensors are bf16, 0 if f32
// flags[1] = 1 if edge_index is int64, 0 if int32
// R22: 64-lane parallel scan + ballot (was a serial single-lane loop).
__global__ void detect_k(const void* x, const void* ei, int* flags) {
    const int t = threadIdx.x;  // 64 threads
    const __hip_bfloat16* xb = (const __hip_bfloat16*)x;
    int bad = 0;
#pragma unroll
    for (int i = 0; i < 16; ++i) {
        const float v = fabsf(__bfloat162float(xb[t + i * 64]));
        if (!(v < 1e6f)) bad = 1;  // catches big values AND NaN
    }
    const unsigned long long b = __ballot(bad);
    if (t == 0) {
        flags[0] = (b == 0ull) ? 1 : 0;
        const int* e32 = (const int*)ei;
        int orv = e32[1] | e32[3] | e32[5] | e32[7] | e32[9] | e32[11];
        flags[1] = (orv == 0) ? 1 : 0;
    }
}

// x -> tiled h planes + blocked hB plane; pad rows zeroed
__global__ void conv_h0_k(const void* x, ushort* HH, ushort* HL, ushort* hB,
                          const int* flags, int useHL, int Nn, size_t npad256) {
    size_t i = (size_t)blockIdx.x * blockDim.x + threadIdx.x;
    if (i >= npad256) return;
    const int n = (int)(i >> 8), k = (int)(i & 255);
    float v = 0.f;
    if (n < Nn) v = ldf(x, i, flags[0]);
    const ushort hi = f2bs(v);
    const ushort lo = f2bs(v - bs2f(hi));
    const size_t a = taddrH(n, k);
    HH[a] = hi;
    if (useHL) HL[a] = lo;
    hB[(size_t)n * 512 + k] = hi;
    hB[(size_t)n * 512 + 256 + k] = lo;
}

// tiled h planes -> blocked hB. Each thread moves one 8-half fragment (16B)
// of hi + the matching lo.
__global__ void repack_k(const ushort* __restrict__ TH, const ushort* __restrict__ TL,
                         ushort* __restrict__ hB, int useHL, int ngroups) {
    const int g = blockIdx.x * 256 + threadIdx.x;
    if (g >= ngroups) return;
    const int t = g >> 9, o = (g & 511) * 8;
    const int k = ((o >> 9) << 5) | (((o >> 7) & 3) << 3);
    const int n = t * 16 + ((o >> 3) & 15);
    const uint4 hv = *(const uint4*)&TH[(size_t)t * 4096 + o];
    *(uint4*)&hB[(size_t)n * 512 + k] = hv;
    uint4 lv;
    if (useHL) lv = *(const uint4*)&TL[(size_t)t * 4096 + o];
    else       lv = make_uint4(0u, 0u, 0u, 0u);
    *(uint4*)&hB[(size_t)n * 512 + 256 + k] = lv;
}

// WihP[l][r][k] = sum_j Wih[r][j] * W[l][k][j]  (f32, 16x16-tiled, LDS-staged)
__global__ __launch_bounds__(256)
void prep1_k(const void* wih, const void* w, float* wihp, const int* flags) {
    __shared__ float As[16][260], Bs[16][260];
    const int bx = blockIdx.x;            // l*768 + rt16*16 + kt16
    const int l = bx / 768, rem = bx % 768;
    const int rt = (rem >> 4) << 4, kt = (rem & 15) << 4;
    const int tid = threadIdx.x, isbf = flags[0];
    for (int idx = tid; idx < 4096; idx += 256) {
        const int row = idx >> 8, col = idx & 255;
        As[row][col] = ldf(wih, (size_t)(rt + row) * 256 + col, isbf);
        Bs[row][col] = ldf(w, (size_t)l * 65536 + (size_t)(kt + row) * 256 + col, isbf);
    }
    __syncthreads();
    const int ri = tid >> 4, ki = tid & 15;
    float acc = 0.f;
    for (int j = 0; j < 256; ++j) acc = fmaf(As[ri][j], Bs[ki][j], acc);
    wihp[((size_t)l * 768 + rt + ri) * 256 + kt + ki] = acc;
}

// Build tiled gate-B matrices + biases.
// BgA[l] [1024 out][512 k] (k segs = S hi / S lo), out col j: g=(j>>4)&3,
//   b=16*(j>>6)+(j&15): g in {r,z,ni}: WihP[l][g*256+b][kk]; nh: 0.
// BgB (shared) [1024 out][512 k] (k segs = h hi / h lo): g in {r,z}:
//   Whh[g*256+b][kk]; nh: Whh[512+b][kk]; ni: 0.
__global__ void prep2_k(const float* __restrict__ wihp, const void* whh,
                        const void* bih, const void* bhh,
                        ushort* BgAH, ushort* BgAL, ushort* BgBH, ushort* BgBL,
                        float* bsum, float* bni, float* bnh,
                        const int* flags, int L) {
    const int i = blockIdx.x * blockDim.x + threadIdx.x;
    const int isbf = flags[0];
    if (i < (L << 19)) {
        const int l = i >> 19, r2 = i & 524287;
        const int j = r2 >> 9, k = r2 & 511;
        const int g = (j >> 4) & 3, b = ((j >> 6) << 4) + (j & 15);
        const int kk = k & 255;
        const float v = (g == 3) ? 0.f
                      : wihp[((size_t)l * 768 + g * 256 + b) * 256 + kk];
        const ushort hi = f2bs(v);
        const int ct = j >> 4, c = k >> 5;
        const size_t a = (size_t)l * 524288 + (size_t)(ct * 16 + c) * 512
                       + (size_t)(((k >> 3) & 3) << 7) + ((j & 15) << 3) + (k & 7);
        BgAH[a] = hi; BgAL[a] = f2bs(v - bs2f(hi));
    }
    if (i < 524288) {
        const int j = i >> 9, k = i & 511;
        const int g = (j >> 4) & 3, b = ((j >> 6) << 4) + (j & 15);
        const int kk = k & 255;
        float v;
        if (g == 0)      v = ldf(whh, (size_t)b * 256 + kk, isbf);
        else if (g == 1) v = ldf(whh, (size_t)(256 + b) * 256 + kk, isbf);
        else if (g == 2) v = 0.f;
        else             v = ldf(whh, (size_t)(512 + b) * 256 + kk, isbf);
        const ushort hi = f2bs(v);
        const int ct = j >> 4, c = k >> 5;
        const size_t a = (size_t)(ct * 16 + c) * 512
                       + (size_t)(((k >> 3) & 3) << 7) + ((j & 15) << 3) + (k & 7);
        BgBH[a] = hi; BgBL[a] = f2bs(v - bs2f(hi));
    }
    if (i < 512) bsum[i] = ldf(bih, i, isbf) + ldf(bhh, i, isbf);
    if (i < 256) {
        bni[i] = ldf(bih, 512 + i, isbf);
        bnh[i] = ldf(bhh, 512 + i, isbf);
    }
}

// ---------------- CSR build (by dst), once per call ----------------

__global__ void zero_int_k(int* p, int n) {
    int i = blockIdx.x * blockDim.x + threadIdx.x;
    if (i < n) p[i] = 0;
}

__global__ void count_k(const void* ei, int* cnt, const int* flags, int E) {
    int e = blockIdx.x * blockDim.x + threadIdx.x;
    if (e >= E) return;
    const int* e32 = (const int*)ei;
    int d = flags[1] ? e32[2 * ((size_t)E + e)] : e32[(size_t)E + e];
    atomicAdd(&cnt[d], 1);
}

__global__ __launch_bounds__(256)
void scan1_k(const int* cnt, int* ptr, int* bsumN, int N) {
    __shared__ int s[256];
    const int t = threadIdx.x;
    const int gid = blockIdx.x * 256 + t;
    int v = (gid < N) ? cnt[gid] : 0;
    const int own = v;
    s[t] = v;
    __syncthreads();
#pragma unroll
    for (int off = 1; off < 256; off <<= 1) {
        int add = (t >= off) ? s[t - off] : 0;
        __syncthreads();
        s[t] += add;
        __syncthreads();
    }
    if (gid < N) ptr[gid] = s[t] - own;
    if (t == 255) bsumN[blockIdx.x] = s[255];
}

__global__ __launch_bounds__(256)
void scan2_k(int* bsumN, int NB) {
    __shared__ int s[256];
    __shared__ int carry;
    const int t = threadIdx.x;
    if (t == 0) carry = 0;
    __syncthreads();
    for (int base = 0; base < NB; base += 256) {
        const int i = base + t;
        int v = (i < NB) ? bsumN[i] : 0;
        const int own = v;
        s[t] = v;
        __syncthreads();
#pragma unroll
        for (int off = 1; off < 256; off <<= 1) {
            int add = (t >= off) ? s[t - off] : 0;
            __syncthreads();
            s[t] += add;
            __syncthreads();
        }
        if (i < NB) bsumN[i] = carry + s[t] - own;
        __syncthreads();
        if (t == 0) carry += s[255];
        __syncthreads();
    }
}

__global__ void scan3_k(int* ptr, int* cursor, const int* bsumN, int N, int E) {
    const int gid = blockIdx.x * 256 + threadIdx.x;
    if (gid < N) {
        const int p = ptr[gid] + bsumN[blockIdx.x];
        ptr[gid] = p;
        cursor[gid] = p;
    }
    if (gid == 0) ptr[N] = E;
}

__global__ void fill_k(const void* ei, const void* ew, int* cursor,
                       int* srcs, float* wse, const int* flags, int E) {
    int e = blockIdx.x * blockDim.x + threadIdx.x;
    if (e >= E) return;
    const int* e32 = (const int*)ei;
    int s, d;
    if (flags[1]) { s = e32[2 * (size_t)e]; d = e32[2 * ((size_t)E + e)]; }
    else          { s = e32[e];             d = e32[(size_t)E + e]; }
    const int p = atomicAdd(&cursor[d], 1);
    srcs[p] = s;
    wse[p] = ldf(ew, e, flags[0]);
}

// ---------------- SpMM gather: S[d] = sum_j w_j * h[src_j] ------------------
// hB blocked [n][512] (hi row | lo row): ONE 16B load per lane per edge.
// unroll-4: four independent gather loads in flight before any FMA.
__global__ __launch_bounds__(256)
void spmm_k(const ushort* __restrict__ hB, const int* __restrict__ ptr,
            const int* __restrict__ srcs, const float* __restrict__ wse,
            ushort* __restrict__ AGG, int N) {
    const int node = blockIdx.x * 4 + (threadIdx.x >> 6);
    if (node >= N) return;
    const int lane = threadIdx.x & 63;
    const int p0 = ptr[node], p1 = ptr[node + 1];
    float av[8];
#pragma unroll
    for (int i = 0; i < 8; ++i) av[i] = 0.f;
    union U8 { ushort u[8]; uint4 v; };
    int j = p0;
    for (; j + 3 < p1; j += 4) {
        const int s0 = srcs[j], s1 = srcs[j + 1], s2 = srcs[j + 2], s3 = srcs[j + 3];
        const float w0 = wse[j], w1 = wse[j + 1], w2 = wse[j + 2], w3 = wse[j + 3];
        U8 u0, u1, u2, u3;
        u0.v = *(const uint4*)&hB[(size_t)s0 * 512 + lane * 8];
        u1.v = *(const uint4*)&hB[(size_t)s1 * 512 + lane * 8];
        u2.v = *(const uint4*)&hB[(size_t)s2 * 512 + lane * 8];
        u3.v = *(const uint4*)&hB[(size_t)s3 * 512 + lane * 8];
#pragma unroll
        for (int i = 0; i < 8; ++i) av[i] = fmaf(w0, bs2f(u0.u[i]), av[i]);
#pragma unroll
        for (int i = 0; i < 8; ++i) av[i] = fmaf(w1, bs2f(u1.u[i]), av[i]);
#pragma unroll
        for (int i = 0; i < 8; ++i) av[i] = fmaf(w2, bs2f(u2.u[i]), av[i]);
#pragma unroll
        for (int i = 0; i < 8; ++i) av[i] = fmaf(w3, bs2f(u3.u[i]), av[i]);
    }
    for (; j < p1; ++j) {
        const int s0 = srcs[j];
        const float w0 = wse[j];
        U8 u0;
        u0.v = *(const uint4*)&hB[(size_t)s0 * 512 + lane * 8];
#pragma unroll
        for (int i = 0; i < 8; ++i) av[i] = fmaf(w0, bs2f(u0.u[i]), av[i]);
    }
#pragma unroll
    for (int i = 0; i < 8; ++i) av[i] += __shfl_xor(av[i], 32);
    if (lane < 32) {
        const int k0 = lane * 8;
        union U8 hi8, lo8;
#pragma unroll
        for (int i = 0; i < 8; ++i) {
            const ushort hi = f2bs(av[i]);
            hi8.u[i] = hi;
            lo8.u[i] = f2bs(av[i] - bs2f(hi));
        }
        *(uint4*)&AGG[taddrA(node, k0)] = hi8.v;
        *(uint4*)&AGG[taddrA(node, 256 + k0)] = lo8.v;
    }
}

// ---------------- gates GEMM + fused GRU (R12 2-slab, proven 160.5us) -------
// A = [S hi (c0..7) | S lo (c8..15) | hH (c16..23) | hL (c24..31)], all
// TILED planes, uniform-base contiguous glds staging. B = BgA[l] for c<16,
// BgB shared for c>=16 (16 chunks each, ct-row stride 8192). BK=64: two
// BK=32 slabs per barrier pair (48KB LDS). JSKIP=3 (nh zero on S segs),
// JSKIP=2 (ni zero on h segs); lo-B only on A-hi regions (skip lo*lo).
// All skip conditions wave-uniform -> glds safe.
__global__ __launch_bounds__(256)
void gates_k(const ushort* __restrict__ AGG,
             const ushort* __restrict__ HH, const ushort* __restrict__ HL,
             const ushort* __restrict__ BgAH, const ushort* __restrict__ BgAL,
             const ushort* __restrict__ BgBH, const ushort* __restrict__ BgBL,
             const float* __restrict__ bsum, const float* __restrict__ bni,
             const float* __restrict__ bnh,
             ushort* __restrict__ HnH, ushort* __restrict__ HnL,
             const int* __restrict__ flags, int useHL, int nRB) {
    __shared__ ushort lds[24576];  // 2 slabs x (A 4096 | Bh 4096 | Bl 4096)
    const int x = blockIdx.x & 7, rem = blockIdx.x >> 3;
    const int cgB = rem & 7, rbHi = rem >> 3;
    const int rb = rbHi * 8 + x;
    if (rb >= nRB) return;
    const int tid = threadIdx.x, lane = tid & 63;
    const int wv = __builtin_amdgcn_readfirstlane(tid >> 6);
    const int wr = wv & 1, wc = wv >> 1;
    const int lm = lane & 15, lq = lane >> 4;
    const int fullsplit = !flags[0];
    const int rt = rb * 8, t0 = 2 * wv;
    f32x4 acc[4][4];
#pragma unroll
    for (int i = 0; i < 4; ++i)
#pragma unroll
        for (int j = 0; j < 4; ++j) acc[i][j] = (f32x4){0.f, 0.f, 0.f, 0.f};

// One BK=64 step = local chunks c0l, c0l+1 of B matrix {BH,BL} (NC=16).
#define GT_STEP(BH, BL, c0l, A0, ASTRIDE, JSKIP, DOLO)                         \
    do {                                                                       \
        __syncthreads();                                                       \
        GLD16((A0) + (size_t)lane * 8, &lds[t0 * 512]);                        \
        GLD16((A0) + (ASTRIDE) + (size_t)lane * 8, &lds[t0 * 512 + 512]);      \
        GLD16((A0) + 512 + (size_t)lane * 8, &lds[12288 + t0 * 512]);          \
        GLD16((A0) + (ASTRIDE) + 512 + (size_t)lane * 8, &lds[12288 + t0 * 512 + 512]); \
        const size_t bb = ((size_t)(8 * cgB + t0) * 16 + (size_t)(c0l)) * 512; \
        if ((t0 & 3) != (JSKIP)) {                                             \
            GLD16((BH) + bb + (size_t)lane * 8, &lds[4096 + t0 * 512]);        \
            GLD16((BH) + bb + 512 + (size_t)lane * 8, &lds[12288 + 4096 + t0 * 512]); \
        }                                                                      \
        if (((t0 + 1) & 3) != (JSKIP)) {                                       \
            GLD16((BH) + bb + 8192 + (size_t)lane * 8, &lds[4096 + t0 * 512 + 512]); \
            GLD16((BH) + bb + 8704 + (size_t)lane * 8, &lds[12288 + 4096 + t0 * 512 + 512]); \
        }                                                                      \
        if (DOLO) {                                                            \
            if ((t0 & 3) != (JSKIP)) {                                         \
                GLD16((BL) + bb + (size_t)lane * 8, &lds[8192 + t0 * 512]);    \
                GLD16((BL) + bb + 512 + (size_t)lane * 8, &lds[12288 + 8192 + t0 * 512]); \
            }                                                                  \
            if (((t0 + 1) & 3) != (JSKIP)) {                                   \
                GLD16((BL) + bb + 8192 + (size_t)lane * 8, &lds[8192 + t0 * 512 + 512]); \
                GLD16((BL) + bb + 8704 + (size_t)lane * 8, &lds[12288 + 8192 + t0 * 512 + 512]); \
            }                                                                  \
        }                                                                      \
        __syncthreads();                                                       \
        _Pragma("unroll")                                                      \
        for (int sb = 0; sb < 2; ++sb) {                                       \
            const int lb = sb * 12288;                                         \
            bf16x8 af[4];                                                      \
            _Pragma("unroll")                                                  \
            for (int i = 0; i < 4; ++i)                                        \
                af[i] = ldfrag(&lds[lb + (4 * wr + i) * 512 + lq * 128 + lm * 8]); \
            _Pragma("unroll")                                                  \
            for (int j = 0; j < 4; ++j) {                                      \
                if (j == (JSKIP)) continue;                                    \
                const bf16x8 bj = ldfrag(&lds[lb + 4096 + (4 * wc + j) * 512 + lq * 128 + lm * 8]); \
                _Pragma("unroll")                                              \
                for (int i = 0; i < 4; ++i) acc[i][j] = MFMA(af[i], bj, acc[i][j]); \
            }                                                                  \
            if (DOLO) {                                                        \
                _Pragma("unroll")                                              \
                for (int j = 0; j < 4; ++j) {                                  \
                    if (j == (JSKIP)) continue;                                \
                    const bf16x8 bl = ldfrag(&lds[lb + 8192 + (4 * wc + j) * 512 + lq * 128 + lm * 8]); \
                    _Pragma("unroll")                                          \
                    for (int i = 0; i < 4; ++i) acc[i][j] = MFMA(af[i], bl, acc[i][j]); \
                }                                                              \
            }                                                                  \
        }                                                                      \
    } while (0)

    // region 0: chunks 0..7   A = S hi (lo-B if fullsplit)
    for (int s = 0; s < 4; ++s) {
        const ushort* a0 = AGG + (size_t)(rt + t0) * 8192 + (size_t)(2 * s) * 512;
        GT_STEP(BgAH, BgAL, 2 * s, a0, 8192, 3, fullsplit);
    }
    // region 1: chunks 8..15  A = S lo (no lo-B: lo*lo dropped)
    for (int s = 4; s < 8; ++s) {
        const ushort* a0 = AGG + (size_t)(rt + t0) * 8192 + (size_t)(2 * s) * 512;
        GT_STEP(BgAH, BgAL, 2 * s, a0, 8192, 3, 0);
    }
    // region 2: chunks 16..23 A = hH tiled (lo-B if fullsplit)
    for (int s = 8; s < 12; ++s) {
        const ushort* a0 = HH + (size_t)(rt + t0) * 4096 + (size_t)(2 * s - 16) * 512;
        GT_STEP(BgBH, BgBL, 2 * s - 16, a0, 4096, 2, fullsplit);
    }
    // region 3: chunks 24..31 A = hL tiled (no lo-B)
    if (useHL) {
        for (int s = 12; s < 16; ++s) {
            const ushort* a0 = HL + (size_t)(rt + t0) * 4096 + (size_t)(2 * s - 24) * 512;
            GT_STEP(BgBH, BgBL, 2 * s - 16, a0, 4096, 2, 0);
        }
    }
#undef GT_STEP

    // GRU epilogue: col-tile 0..3 = r,z,ni,nh for hidden unit b
    const int b = (2 * cgB + wc) * 16 + lm;
    const float rbias = bsum[b], zbias = bsum[256 + b];
    const float ibias = bni[b], hbias = bnh[b];
#pragma unroll
    for (int i = 0; i < 4; ++i) {
        const int row0 = rb * 128 + wr * 64 + i * 16 + lq * 4;
#pragma unroll
        for (int v = 0; v < 4; ++v) {
            const int row = row0 + v;
            const size_t ho = taddrH(row, b);  // buffers padded; pads benign
            float hold = bs2f(HH[ho]);
            if (useHL) hold += bs2f(HL[ho]);
            const float r = 1.f / (1.f + expf(-(acc[i][0][v] + rbias)));
            const float z = 1.f / (1.f + expf(-(acc[i][1][v] + zbias)));
            const float nn = tanhf(acc[i][2][v] + ibias + r * (acc[i][3][v] + hbias));
            const float hv = (1.f - z) * nn + z * hold;
            const ushort hi = f2bs(hv);
            HnH[ho] = hi;
            if (useHL) HnL[ho] = f2bs(hv - bs2f(hi));
        }
    }
}

// out[n] = sum_t relu(h[n,t]) * fc_w[t] + fc_b
// R22: one wave per node (4 nodes/block); lane owns 4 contiguous cols
// (one ushort4 from the tiled plane); pure shfl reduce, no LDS/sync.
__global__ void final_k(const ushort* __restrict__ HH, const ushort* __restrict__ HL,
                        const void* fcw, const void* fcb,
                        void* out, const int* flags, int useHL, int N) {
    const int node = blockIdx.x * 4 + (threadIdx.x >> 6);
    if (node >= N) return;
    const int lane = threadIdx.x & 63;
    const int isbf = flags[0];
    const int k0 = lane * 4;
    const size_t a = taddrH(node, k0);  // 4 consecutive k: contiguous ushort4
    const ushort4 h4 = *(const ushort4*)&HH[a];
    float h0 = bs2f(h4.x), h1 = bs2f(h4.y), h2 = bs2f(h4.z), h3 = bs2f(h4.w);
    if (useHL) {
        const ushort4 l4 = *(const ushort4*)&HL[a];
        h0 += bs2f(l4.x); h1 += bs2f(l4.y); h2 += bs2f(l4.z); h3 += bs2f(l4.w);
    }
    float v = fmaxf(h0, 0.f) * ldf(fcw, k0, isbf)
            + fmaxf(h1, 0.f) * ldf(fcw, k0 + 1, isbf)
            + fmaxf(h2, 0.f) * ldf(fcw, k0 + 2, isbf)
            + fmaxf(h3, 0.f) * ldf(fcw, k0 + 3, isbf);
#pragma unroll
    for (int off = 32; off >= 1; off >>= 1) v += __shfl_down(v, off);
    if (lane == 0) {
        const float s = v + ldf(fcb, 0, isbf);
        if (isbf) ((__hip_bfloat16*)out)[node] = __float2bfloat16(s);
        else      ((float*)out)[node] = s;
    }
}

extern "C" void kernel_launch(void* const* d_in, const int* in_sizes, int n_in,
                              void* d_out, int out_size, void* d_ws, size_t ws_size,
                              hipStream_t stream) {
    const int H = HDIM;
    const int N = in_sizes[0] / H;       // 50000
    const int E = in_sizes[2];           // 800000
    const int L = in_sizes[3] / (H * H); // 5
    const int NB = (N + 255) / 256;
    const int nRB = (N + 127) / 128;     // 391
    const size_t NPAD = (size_t)nRB * 128;
    const size_t hHalf = NPAD * 256;     // halves per tiled h plane
    const size_t aggHalf = NPAD * 512;

    char* p = (char*)d_ws;
    int*    flags = (int*)p;              p += 64;
    ushort* AGG  = (ushort*)p;            p += aggHalf * 2;
    ushort* HxH  = (ushort*)p;            p += hHalf * 2;
    ushort* HyH  = (ushort*)p;            p += hHalf * 2;
    ushort* hB   = (ushort*)p;            p += NPAD * 512 * 2;   // blocked plane
    float*  wihp = (float*)p;             p += (size_t)L * 768 * 256 * 4;
    ushort* BgAH = (ushort*)p;            p += (size_t)L * 524288 * 2;
    ushort* BgAL = (ushort*)p;            p += (size_t)L * 524288 * 2;
    ushort* BgBH = (ushort*)p;            p += (size_t)524288 * 2;
    ushort* BgBL = (ushort*)p;            p += (size_t)524288 * 2;
    float*  bsum = (float*)p;             p += 512 * 4;
    float*  bni  = (float*)p;             p += 256 * 4;
    float*  bnh  = (float*)p;             p += 256 * 4;
    int*    ptr  = (int*)p;               p += (size_t)(N + 1) * 4;
    int*    cursor = (int*)p;             p += (size_t)N * 4;
    int*    bsumN  = (int*)p;             p += (size_t)NB * 4;
    int*    srcs   = (int*)p;             p += (size_t)E * 4;
    float*  wse    = (float*)p;           p += (size_t)E * 4;
    const size_t need_reduced = (size_t)(p - (char*)d_ws);
    ushort* HxL = (ushort*)p;             // optional hi/lo tiled h planes
    ushort* HyL = (ushort*)(p + hHalf * 2);
    const size_t need_full = need_reduced + 2 * hHalf * 2;
    const int useHL = (ws_size >= need_full) ? 1 : 0;
    if (!useHL) { HxL = HxH; HyL = HyH; }  // never dereferenced when useHL=0

    detect_k<<<dim3(1), dim3(64), 0, stream>>>(d_in[0], d_in[1], flags);
    conv_h0_k<<<dim3((unsigned)NPAD), dim3(256), 0, stream>>>(
        d_in[0], HxH, HxL, hB, flags, useHL, N, NPAD * 256);
    prep1_k<<<dim3((unsigned)(L * 768)), dim3(256), 0, stream>>>(
        d_in[4], d_in[3], wihp, flags);
    prep2_k<<<dim3((unsigned)(L * 2048)), dim3(256), 0, stream>>>(
        wihp, d_in[5], d_in[6], d_in[7],
        BgAH, BgAL, BgBH, BgBL, bsum, bni, bnh, flags, L);

    zero_int_k<<<dim3(NB), dim3(256), 0, stream>>>(cursor, N);
    count_k<<<dim3((E + 255) / 256), dim3(256), 0, stream>>>(d_in[1], cursor, flags, E);
    scan1_k<<<dim3(NB), dim3(256), 0, stream>>>(cursor, ptr, bsumN, N);
    scan2_k<<<dim3(1), dim3(256), 0, stream>>>(bsumN, NB);
    scan3_k<<<dim3(NB), dim3(256), 0, stream>>>(ptr, cursor, bsumN, N, E);
    fill_k<<<dim3((E + 255) / 256), dim3(256), 0, stream>>>(
        d_in[1], d_in[2], cursor, srcs, wse, flags, E);

    const dim3 blk(256);
    const unsigned gGrid = 64u * (unsigned)((nRB + 7) / 8);
    const int ngroups = (int)(NPAD * 32);      // fragments per plane
    const unsigned rGrid = (unsigned)((ngroups + 255) / 256);
    ushort *HcH = HxH, *HcL = HxL, *HnH = HyH, *HnL = HyL;
    for (int l = 0; l < L; ++l) {
        spmm_k<<<dim3((N + 3) / 4), blk, 0, stream>>>(hB, ptr, srcs, wse, AGG, N);
        gates_k<<<dim3(gGrid), blk, 0, stream>>>(
            AGG, HcH, HcL,
            BgAH + (size_t)l * 524288, BgAL + (size_t)l * 524288,
            BgBH, BgBL, bsum, bni, bnh, HnH, HnL, flags, useHL, nRB);
        if (l + 1 < L)
            repack_k<<<dim3(rGrid), blk, 0, stream>>>(HnH, HnL, hB, useHL, ngroups);
        ushort* t;
        t = HcH; HcH = HnH; HnH = t;
        t = HcL; HcL = HnL; HnL = t;
    }
    final_k<<<dim3((N + 3) / 4), blk, 0, stream>>>(
        HcH, HcL, d_in[8], d_in[9], d_out, flags, useHL, N);
}